// Round 2
// baseline (1079.422 us; speedup 1.0000x reference)
//
#include <hip/hip_runtime.h>
#include <hip/hip_bf16.h>

constexpr int LYR  = 4;
constexpr int DM   = 384;
constexpr int HIDN = 1536;
constexpr int NHEAD = 6;
constexpr int HDIM = 64;
constexpr int NEXP = 8;
constexpr int SEQ  = 197;
constexpr int BATCH = 8;
constexpr int TOK  = BATCH * SEQ;   // 1576
constexpr int NCLS = 1000;
constexpr int CAPE = TOK;           // max pairs per expert
constexpr int NPATCH = BATCH * 196; // 1568
constexpr float EPSLN = 1e-5f;
constexpr int KP = 40;              // LDS row pitch (bf16 elems) for patch staging

typedef __attribute__((ext_vector_type(8))) short short8v;
typedef __attribute__((ext_vector_type(4))) short short4v;
typedef __attribute__((ext_vector_type(4))) float f32x4v;

// ---------------- threefry2x32 (JAX-compatible) ----------------
__host__ __device__ inline void tf2x32(unsigned k0, unsigned k1, unsigned x0, unsigned x1,
                                       unsigned& y0, unsigned& y1) {
  unsigned ks2 = k0 ^ k1 ^ 0x1BD11BDAu;
  unsigned v0 = x0 + k0, v1 = x1 + k1;
#define TFR(r) { v0 += v1; v1 = (v1 << (r)) | (v1 >> (32 - (r))); v1 ^= v0; }
  TFR(13) TFR(15) TFR(26) TFR(6)
  v0 += k1;  v1 += ks2 + 1u;
  TFR(17) TFR(29) TFR(16) TFR(24)
  v0 += ks2; v1 += k0 + 2u;
  TFR(13) TFR(15) TFR(26) TFR(6)
  v0 += k0;  v1 += k1 + 3u;
  TFR(17) TFR(29) TFR(16) TFR(24)
  v0 += k1;  v1 += ks2 + 4u;
  TFR(13) TFR(15) TFR(26) TFR(6)
  v0 += ks2; v1 += k0 + 5u;
#undef TFR
  y0 = v0; y1 = v1;
}

// XLA ErfInv32 (Giles) — matches jax.lax.erf_inv for f32
__device__ inline float erfinv32(float x) {
  float w = -log1pf(-x * x);
  float p;
  if (w < 5.f) {
    w -= 2.5f;
    p = 2.81022636e-08f;
    p = fmaf(p, w, 3.43273939e-07f);
    p = fmaf(p, w, -3.5233877e-06f);
    p = fmaf(p, w, -4.39150654e-06f);
    p = fmaf(p, w, 0.00021858087f);
    p = fmaf(p, w, -0.00125372503f);
    p = fmaf(p, w, -0.00417768164f);
    p = fmaf(p, w, 0.246640727f);
    p = fmaf(p, w, 1.50140941f);
  } else {
    w = sqrtf(w) - 3.f;
    p = -0.000200214257f;
    p = fmaf(p, w, 0.000100950558f);
    p = fmaf(p, w, 0.00134934322f);
    p = fmaf(p, w, -0.00367342844f);
    p = fmaf(p, w, 0.00573950773f);
    p = fmaf(p, w, -0.0076224613f);
    p = fmaf(p, w, 0.00943887047f);
    p = fmaf(p, w, 1.00167406f);
    p = fmaf(p, w, 2.83297682f);
  }
  return p * x;
}

__device__ inline float gelu_f(float x) {
  return 0.5f * x * (1.f + erff(x * 0.70710678118654752f));
}

__device__ inline unsigned short bf16_rne(float x) {
  unsigned u = __float_as_uint(x);
  unsigned r = (u + 0x7fffu + ((u >> 16) & 1u)) >> 16;
  return (unsigned short)r;
}
__device__ inline void split2(float x, short& hs, short& ls) {
  unsigned hu = bf16_rne(x);
  float hf = __uint_as_float(hu << 16);
  unsigned lu = bf16_rne(x - hf);
  hs = (short)hu; ls = (short)lu;
}

// =====================================================================
// Weight pre-conversion: W[K][N] fp32 -> MFMA A-frag chunks, hi/lo bf16.
// =====================================================================
__global__ __launch_bounds__(256) void convw_kernel(const float* __restrict__ src,
                                                    short* __restrict__ dst,
                                                    int K, int N) {
  const int nchunks = (K >> 5) * (N >> 4);
  const int chunk = blockIdx.x * 4 + (threadIdx.x >> 6);
  if (chunk >= nchunks) return;
  const int lane = threadIdx.x & 63;
  const long eoffS = (long)blockIdx.y * K * N;
  const long eoffD = (long)blockIdx.y * nchunks * 1024;
  const int nc = N >> 4;
  const int kt = chunk / nc, nt = chunk - kt * nc;
  const int n = nt * 16 + (lane & 15);
  const int kb = kt * 32 + (lane >> 4) * 8;
  short8v hv, lv;
#pragma unroll
  for (int j = 0; j < 8; j++) {
    short h, l;
    split2(src[eoffS + (long)(kb + j) * N + n], h, l);
    hv[j] = h; lv[j] = l;
  }
  *(short8v*)&dst[eoffD + (long)chunk * 1024 + lane * 8] = hv;
  *(short8v*)&dst[eoffD + (long)chunk * 1024 + 512 + lane * 8] = lv;
}

// =====================================================================
// Barrier-free MFMA GEMM: A pre-split (Ah/Al row-major [row][K]), W frags.
// No LDS, no __syncthreads. MODE: 0 dense, 1 moe1 (gelu->bf16 split out),
// 2 moe2. Grid: (strips, m_tiles); strip fast-dim => same-strip M-blocks
// land on the same XCD (ids differ by multiples of 8 when strips%8==0).
// =====================================================================
template <int KTOT, int NTOT, int MODE>
__global__ __launch_bounds__(256) void gemm_frag_kernel(
    const short* __restrict__ Ah, const short* __restrict__ Al,
    const short* __restrict__ Wf, const float* __restrict__ bias,
    const int* __restrict__ lists, const int* __restrict__ counts,
    float* __restrict__ outF, short* __restrict__ outH, short* __restrict__ outL) {
  constexpr int SPE = NTOT / 64;  // strips per expert
  const int strip = blockIdx.x;
  const int e = MODE ? (strip / SPE) : 0;
  const int c0 = (MODE ? (strip - e * SPE) : strip) * 64;
  const int m = blockIdx.y;
  int cnt = TOK;
  if (MODE) cnt = counts[e];
  if (m * 64 >= cnt) return;
  const int tid = threadIdx.x;
  const int w = tid >> 6, lane = tid & 63;
  const int wm = (w >> 1) * 32, wn = (w & 1) * 32;
  const int tl = lane & 15, kq = (lane >> 4) * 8;
  int pid[2]; long arow[2];
#pragma unroll
  for (int tt = 0; tt < 2; ++tt) {
    const int r = m * 64 + wm + tt * 16 + tl;
    int p;
    if (MODE) {
      p = (r < cnt) ? lists[e * CAPE + r] : -1;
      const int rr = (p < 0) ? 0 : ((MODE == 1) ? (p >> 1) : p);
      arow[tt] = (long)rr * KTOT;
    } else {
      p = (r < TOK) ? r : -1;
      arow[tt] = (long)((p < 0) ? 0 : r) * KTOT;
    }
    pid[tt] = p;
  }
  const short* W = Wf + (long)e * ((KTOT >> 5) * (NTOT >> 4)) * 1024;
  f32x4v Cr[2][2] = {};
#pragma unroll 4
  for (int kt = 0; kt < KTOT / 32; ++kt) {
    short8v bh[2], bl[2];
#pragma unroll
    for (int tt = 0; tt < 2; ++tt) {
      bh[tt] = *(const short8v*)&Ah[arow[tt] + kt * 32 + kq];
      bl[tt] = *(const short8v*)&Al[arow[tt] + kt * 32 + kq];
    }
    const long wkb = ((long)kt * (NTOT >> 4) + (c0 >> 4) + (wn >> 4)) * 1024;
#pragma unroll
    for (int nt = 0; nt < 2; ++nt) {
      const short8v wh = *(const short8v*)&W[wkb + nt * 1024 + lane * 8];
      const short8v wl = *(const short8v*)&W[wkb + nt * 1024 + 512 + lane * 8];
#pragma unroll
      for (int tt = 0; tt < 2; ++tt) {
        Cr[tt][nt] = __builtin_amdgcn_mfma_f32_16x16x32_bf16(wh, bh[tt], Cr[tt][nt], 0, 0, 0);
        Cr[tt][nt] = __builtin_amdgcn_mfma_f32_16x16x32_bf16(wh, bl[tt], Cr[tt][nt], 0, 0, 0);
        Cr[tt][nt] = __builtin_amdgcn_mfma_f32_16x16x32_bf16(wl, bh[tt], Cr[tt][nt], 0, 0, 0);
      }
    }
  }
  const int nq = (lane >> 4) * 4;
#pragma unroll
  for (int tt = 0; tt < 2; ++tt) {
    if (pid[tt] < 0) continue;
    const long orow = (long)pid[tt] * NTOT;
#pragma unroll
    for (int nt = 0; nt < 2; ++nt) {
      const int n = c0 + wn + nt * 16 + nq;
      const float4 bv = *(const float4*)&bias[(MODE ? e * NTOT : 0) + n];
      float o0 = Cr[tt][nt][0] + bv.x, o1 = Cr[tt][nt][1] + bv.y;
      float o2 = Cr[tt][nt][2] + bv.z, o3 = Cr[tt][nt][3] + bv.w;
      if (MODE == 1) {
        o0 = gelu_f(o0); o1 = gelu_f(o1); o2 = gelu_f(o2); o3 = gelu_f(o3);
        short4v hv, lv; short hs, ls;
        split2(o0, hs, ls); hv[0] = hs; lv[0] = ls;
        split2(o1, hs, ls); hv[1] = hs; lv[1] = ls;
        split2(o2, hs, ls); hv[2] = hs; lv[2] = ls;
        split2(o3, hs, ls); hv[3] = hs; lv[3] = ls;
        *(short4v*)&outH[orow + n] = hv;
        *(short4v*)&outL[orow + n] = lv;
      } else {
        *(float4*)&outF[orow + n] = make_float4(o0, o1, o2, o3);
      }
    }
  }
}

// =====================================================================
// Patch embed as MFMA GEMM (gathers A from x via unfold geometry).
// Epilogue fuses patch_b + pos, writes t fp32 + tfh/tfl bf16 mirrors.
// =====================================================================
__global__ __launch_bounds__(256) void patch_mfma_kernel(const float* __restrict__ x,
                                                         const short* __restrict__ Wf,
                                                         const float* __restrict__ pb,
                                                         const float* __restrict__ pos,
                                                         float* __restrict__ t,
                                                         short* __restrict__ tfh,
                                                         short* __restrict__ tfl) {
  constexpr int KTOT = 768, NTOT = DM;
  const int rowsM = min(64, NPATCH - (int)blockIdx.x * 64);
  const int c0 = blockIdx.z * 64;
  const int tid = threadIdx.x;
  const int w = tid >> 6, lane = tid & 63;
  __shared__ short xh[64 * KP];
  __shared__ short xl[64 * KP];
  const int sr = tid >> 2, skq = (tid & 3) * 8;
  const bool okr = (sr < rowsM);
  const int p = blockIdx.x * 64 + sr;
  const int pbat = okr ? (p / 196) : 0;
  const int pn = okr ? (p - pbat * 196) : 0;
  const int hp = pn / 14, wp = pn - hp * 14;
  const float* xbase = x + ((long)pbat * 3 * 224 + hp * 16) * 224 + wp * 16;
  const int wm = (w >> 1) * 32, wn = (w & 1) * 32;
  f32x4v Cr[2][2] = {};
  float4 ra = make_float4(0.f, 0.f, 0.f, 0.f), rb = ra;
  if (okr) {
    const int f = skq;  // kt = 0
    const int c = f >> 8, py = (f >> 4) & 15, px = f & 15;
    const float* ptr = xbase + ((long)c * 224 + py) * 224 + px;
    ra = *(const float4*)ptr;
    rb = *(const float4*)(ptr + 4);
  }
  for (int kt = 0; kt < KTOT / 32; ++kt) {
    __syncthreads();
    {
      const float v[8] = {ra.x, ra.y, ra.z, ra.w, rb.x, rb.y, rb.z, rb.w};
      short8v hv, lv;
#pragma unroll
      for (int j = 0; j < 8; j++) { short h, l; split2(v[j], h, l); hv[j] = h; lv[j] = l; }
      *(short8v*)&xh[sr * KP + skq] = hv;
      *(short8v*)&xl[sr * KP + skq] = lv;
    }
    if (kt + 1 < KTOT / 32 && okr) {
      const int f = (kt + 1) * 32 + skq;
      const int c = f >> 8, py = (f >> 4) & 15, px = f & 15;
      const float* ptr = xbase + ((long)c * 224 + py) * 224 + px;
      ra = *(const float4*)ptr;
      rb = *(const float4*)(ptr + 4);
    }
    __syncthreads();
    short8v bhv[2], blv[2];
#pragma unroll
    for (int tt = 0; tt < 2; ++tt) {
      const int trow = wm + tt * 16 + (lane & 15);
      bhv[tt] = *(const short8v*)&xh[trow * KP + (lane >> 4) * 8];
      blv[tt] = *(const short8v*)&xl[trow * KP + (lane >> 4) * 8];
    }
    const long wkb = ((long)kt * (NTOT >> 4) + (c0 >> 4) + (wn >> 4)) * 1024;
#pragma unroll
    for (int nt = 0; nt < 2; ++nt) {
      const short8v wh = *(const short8v*)&Wf[wkb + nt * 1024 + lane * 8];
      const short8v wl = *(const short8v*)&Wf[wkb + nt * 1024 + 512 + lane * 8];
#pragma unroll
      for (int tt = 0; tt < 2; ++tt) {
        Cr[tt][nt] = __builtin_amdgcn_mfma_f32_16x16x32_bf16(wh, bhv[tt], Cr[tt][nt], 0, 0, 0);
        Cr[tt][nt] = __builtin_amdgcn_mfma_f32_16x16x32_bf16(wh, blv[tt], Cr[tt][nt], 0, 0, 0);
        Cr[tt][nt] = __builtin_amdgcn_mfma_f32_16x16x32_bf16(wl, bhv[tt], Cr[tt][nt], 0, 0, 0);
      }
    }
  }
  const int tl = lane & 15;
  const int nq = (lane >> 4) * 4;
#pragma unroll
  for (int tt = 0; tt < 2; ++tt) {
    const int trow = wm + tt * 16 + tl;
    if (trow < rowsM) {
      const int r = blockIdx.x * 64 + trow;
      const int b2 = r / 196, n2 = r - b2 * 196;
      const long orow = (long)(b2 * SEQ + 1 + n2) * DM;
#pragma unroll
      for (int nt = 0; nt < 2; ++nt) {
        const int n = c0 + wn + nt * 16 + nq;
        const float4 bv = *(const float4*)&pb[n];
        const float4 pv = *(const float4*)&pos[(1 + n2) * DM + n];
        float o0 = Cr[tt][nt][0] + bv.x + pv.x;
        float o1 = Cr[tt][nt][1] + bv.y + pv.y;
        float o2 = Cr[tt][nt][2] + bv.z + pv.z;
        float o3 = Cr[tt][nt][3] + bv.w + pv.w;
        *(float4*)&t[orow + n] = make_float4(o0, o1, o2, o3);
        short4v hv, lv; short hs, ls;
        split2(o0, hs, ls); hv[0] = hs; lv[0] = ls;
        split2(o1, hs, ls); hv[1] = hs; lv[1] = ls;
        split2(o2, hs, ls); hv[2] = hs; lv[2] = ls;
        split2(o3, hs, ls); hv[3] = hs; lv[3] = ls;
        *(short4v*)&tfh[orow + n] = hv;
        *(short4v*)&tfl[orow + n] = lv;
      }
    }
  }
}

__global__ void cls_pos_kernel(const float* __restrict__ cls, const float* __restrict__ pos,
                               float* __restrict__ t,
                               short* __restrict__ tfh, short* __restrict__ tfl) {
  int b = blockIdx.x, d = threadIdx.x;
  float v = cls[d] + pos[d];
  t[(b * SEQ) * DM + d] = v;
  short hs, ls; split2(v, hs, ls);
  tfh[(b * SEQ) * DM + d] = hs;
  tfl[(b * SEQ) * DM + d] = ls;
}

// =====================================================================
// Tiled attention: one block per (b, h, 32-query tile). Two-pass softmax.
// Output written as bf16 hi/lo split (feeds proj GEMM directly).
// =====================================================================
constexpr int QT = 32;   // queries per block
constexpr int SP = 208;  // S row pitch
__global__ __launch_bounds__(256) void attn_tile_kernel(const float* __restrict__ qkv,
                                                        short* __restrict__ afh,
                                                        short* __restrict__ afl) {
  const int bh = blockIdx.x;
  const int b = bh / NHEAD, h = bh % NHEAD;
  const int q0 = blockIdx.y * QT;
  const int nq = min(QT, SEQ - q0);
  __shared__ float Qs[64][QT + 4];   // d-major
  __shared__ float KV[64][68];       // phase1: KT[d][key]; phase3: Vs[key][d]
  __shared__ float Ss[QT][SP];
  const int tid = threadIdx.x;
  const int tx = tid & 15, ty = tid >> 4;
  for (int i = tid; i < QT * 16; i += 256) {
    const int q = i >> 4, dq = (i & 15) << 2;
    float4 v = make_float4(0.f, 0.f, 0.f, 0.f);
    if (q < nq) v = *(const float4*)&qkv[(long)(b * SEQ + q0 + q) * 1152 + h * HDIM + dq];
    Qs[dq + 0][q] = v.x; Qs[dq + 1][q] = v.y; Qs[dq + 2][q] = v.z; Qs[dq + 3][q] = v.w;
  }
  // ---- phase 1: scores ----
  for (int kt = 0; kt < 4; ++kt) {
    const int kbase = kt * 64;
    __syncthreads();
    for (int i = tid; i < 64 * 16; i += 256) {
      const int key = i >> 4, dq = (i & 15) << 2;
      float4 v = make_float4(0.f, 0.f, 0.f, 0.f);
      if (kbase + key < SEQ)
        v = *(const float4*)&qkv[(long)(b * SEQ + kbase + key) * 1152 + DM + h * HDIM + dq];
      KV[dq + 0][key] = v.x; KV[dq + 1][key] = v.y; KV[dq + 2][key] = v.z; KV[dq + 3][key] = v.w;
    }
    __syncthreads();
    float acc[2][4] = {};
#pragma unroll 16
    for (int d = 0; d < 64; ++d) {
      const float4 k4 = *(const float4*)&KV[d][tx << 2];
      const float a0 = Qs[d][ty * 2], a1 = Qs[d][ty * 2 + 1];
      const float kk[4] = {k4.x, k4.y, k4.z, k4.w};
#pragma unroll
      for (int j = 0; j < 4; j++) {
        acc[0][j] = fmaf(a0, kk[j], acc[0][j]);
        acc[1][j] = fmaf(a1, kk[j], acc[1][j]);
      }
    }
#pragma unroll
    for (int i = 0; i < 2; i++) {
      float4 o = make_float4(acc[i][0] * 0.125f, acc[i][1] * 0.125f,
                             acc[i][2] * 0.125f, acc[i][3] * 0.125f);
      *(float4*)&Ss[ty * 2 + i][kbase + (tx << 2)] = o;
    }
  }
  __syncthreads();
  // ---- phase 2: softmax per row (8 lanes/row) ----
  {
    const int row = tid >> 3, c = tid & 7;
    float m = -1e30f;
    for (int k = c; k < SEQ; k += 8) m = fmaxf(m, Ss[row][k]);
    m = fmaxf(m, __shfl_xor(m, 1)); m = fmaxf(m, __shfl_xor(m, 2)); m = fmaxf(m, __shfl_xor(m, 4));
    float s = 0.f;
    for (int k = c; k < SEQ; k += 8) { float e2 = __expf(Ss[row][k] - m); Ss[row][k] = e2; s += e2; }
    s += __shfl_xor(s, 1); s += __shfl_xor(s, 2); s += __shfl_xor(s, 4);
    const float inv = 1.f / s;
    for (int k = c; k < SEQ; k += 8) Ss[row][k] *= inv;
  }
  // ---- phase 3: O = P@V ----
  float acc[2][4] = {};
  for (int kt = 0; kt < 4; ++kt) {
    const int kbase = kt * 64;
    const int kend = min(64, SEQ - kbase);
    __syncthreads();
    for (int i = tid; i < 64 * 16; i += 256) {
      const int key = i >> 4, dq = (i & 15) << 2;
      float4 v = make_float4(0.f, 0.f, 0.f, 0.f);
      if (kbase + key < SEQ)
        v = *(const float4*)&qkv[(long)(b * SEQ + kbase + key) * 1152 + 2 * DM + h * HDIM + dq];
      *(float4*)&KV[key][dq] = v;
    }
    __syncthreads();
    for (int k = 0; k < kend; ++k) {
      const float4 v4 = *(const float4*)&KV[k][tx << 2];
      const float p0 = Ss[ty * 2][kbase + k], p1 = Ss[ty * 2 + 1][kbase + k];
      const float vv[4] = {v4.x, v4.y, v4.z, v4.w};
#pragma unroll
      for (int j = 0; j < 4; j++) {
        acc[0][j] = fmaf(p0, vv[j], acc[0][j]);
        acc[1][j] = fmaf(p1, vv[j], acc[1][j]);
      }
    }
  }
#pragma unroll
  for (int i = 0; i < 2; i++) {
    const int row = ty * 2 + i;
    if (row < nq) {
      const long o = (long)(b * SEQ + q0 + row) * DM + h * HDIM + (tx << 2);
      short4v hv, lv; short hs, ls;
      split2(acc[i][0], hs, ls); hv[0] = hs; lv[0] = ls;
      split2(acc[i][1], hs, ls); hv[1] = hs; lv[1] = ls;
      split2(acc[i][2], hs, ls); hv[2] = hs; lv[2] = ls;
      split2(acc[i][3], hs, ls); hv[3] = hs; lv[3] = ls;
      *(short4v*)&afh[o] = hv;
      *(short4v*)&afl[o] = lv;
    }
  }
}

// ---------------- residual add + LayerNorm (per token) ----------------
__global__ __launch_bounds__(384) void add_ln_kernel(float* __restrict__ t,
                                                     const float* __restrict__ delta,
                                                     const float* __restrict__ g,
                                                     const float* __restrict__ bta,
                                                     short* __restrict__ tfh,
                                                     short* __restrict__ tfl) {
  int tok = blockIdx.x, d = threadIdx.x;
  float v = t[tok * DM + d] + delta[tok * DM + d];
  float sv = v, sq = v * v;
  for (int off = 32; off > 0; off >>= 1) { sv += __shfl_xor(sv, off); sq += __shfl_xor(sq, off); }
  __shared__ float rs[6], rq[6];
  int w = d >> 6, ln = d & 63;
  if (ln == 0) { rs[w] = sv; rq[w] = sq; }
  __syncthreads();
  float mean = 0.f, ms = 0.f;
#pragma unroll
  for (int i = 0; i < 6; i++) { mean += rs[i]; ms += rq[i]; }
  mean *= (1.f / DM); ms *= (1.f / DM);
  float inv = rsqrtf(ms - mean * mean + EPSLN);
  float y = (v - mean) * inv * g[d] + bta[d];
  t[tok * DM + d] = y;
  short hs, ls; split2(y, hs, ls);
  tfh[tok * DM + d] = hs;
  tfl[tok * DM + d] = ls;
}

// ---------------- router logits + top-2 (no global atomics) ----------------
__global__ __launch_bounds__(256) void router_logits_kernel(const float* __restrict__ t,
                                                            const float* __restrict__ rw,
                                                            const float* __restrict__ rb,
                                                            unsigned k0, unsigned k1,
                                                            float* __restrict__ gates,
                                                            int* __restrict__ idxb) {
  const int tok = blockIdx.x * 4 + (threadIdx.x >> 6);
  const int lane = threadIdx.x & 63;
  const int e = lane & 7, j = lane >> 3;
  const float* xr = t + tok * DM;
  float acc = 0.f;
  for (int d2 = j * 48; d2 < j * 48 + 48; d2++) acc += xr[d2] * rw[d2 * NEXP + e];
  acc += __shfl_xor(acc, 8);
  acc += __shfl_xor(acc, 16);
  acc += __shfl_xor(acc, 32);
  if (lane < 8) {
    acc += rb[e];
    unsigned i = (unsigned)(tok * NEXP + e);
    unsigned y0, y1;
    tf2x32(k0, k1, 0u, i, y0, y1);
    unsigned bits = y0 ^ y1;
    float f = __uint_as_float(0x3f800000u | (bits >> 9)) - 1.0f;
    const float lo = -0.99999994f;
    float u = f * 2.0f + lo;
    u = fmaxf(lo, u);
    acc += 0.01f * (1.41421356f * erfinv32(u));
  }
  float lg[8];
#pragma unroll
  for (int qq = 0; qq < 8; qq++) lg[qq] = __shfl(acc, qq);
  if (lane == 0) {
    int i0 = 0; float v0 = lg[0];
#pragma unroll
    for (int qq = 1; qq < 8; qq++) if (lg[qq] > v0) { v0 = lg[qq]; i0 = qq; }
    int i1 = -1; float v1 = -1e30f;
#pragma unroll
    for (int qq = 0; qq < 8; qq++) if (qq != i0 && lg[qq] > v1) { v1 = lg[qq]; i1 = qq; }
    float e1 = __expf(v1 - v0);
    float g0 = 1.f / (1.f + e1);
    idxb[tok * 2] = i0; idxb[tok * 2 + 1] = i1;
    gates[tok * 2] = g0; gates[tok * 2 + 1] = 1.f - g0;
  }
}

// ---------------- bucket: single block bins all pairs via LDS atomics ----------------
__global__ __launch_bounds__(1024) void bucket_kernel(const int* __restrict__ idxb,
                                                      int* __restrict__ lists,
                                                      int* __restrict__ counts,
                                                      int* __restrict__ occ) {
  __shared__ int lc[NEXP];
  __shared__ int locc[2 * NEXP];
  const int tid = threadIdx.x;
  if (tid < NEXP) lc[tid] = 0;
  if (tid < 2 * NEXP) locc[tid] = 0;
  __syncthreads();
  for (int i = tid; i < 2 * TOK; i += 1024) {
    const int e = idxb[i];
    const int p = atomicAdd(&lc[e], 1);
    lists[e * CAPE + p] = i;
    locc[(i & 1) * NEXP + e] = 1;
  }
  __syncthreads();
  if (tid < NEXP) counts[tid] = lc[tid];
  if (tid < 2 * NEXP) occ[tid] = locc[tid];
}

// ---------------- prep: bias0 = b2 ----------------
__global__ void prep_kernel(const float* __restrict__ b2, float* __restrict__ bias0) {
  int e = blockIdx.x, c = threadIdx.x;
  bias0[e * DM + c] = b2[e * DM + c];
}

// ---------------- bias0 += gelu(b1)@W2 partial over K-chunks ----------------
__global__ __launch_bounds__(384) void bias0_partial_kernel(const float* __restrict__ b1,
                                                            const float* __restrict__ w2,
                                                            float* __restrict__ bias0) {
  const int e = blockIdx.x, kc = blockIdx.y;
  __shared__ float gb[128];
  const int tid = threadIdx.x;
  if (tid < 128) gb[tid] = gelu_f(b1[e * HIDN + kc * 128 + tid]);
  __syncthreads();
  float acc = 0.f;
  const float* W = w2 + ((long)e * HIDN + kc * 128) * DM + tid;
  for (int j2 = 0; j2 < 128; j2++) acc += gb[j2] * W[(long)j2 * DM];
  atomicAdd(&bias0[e * DM + tid], acc);
}

__global__ __launch_bounds__(384) void bias_sum_kernel(const float* __restrict__ bias0,
                                                       const int* __restrict__ occ,
                                                       float* __restrict__ bias_sum) {
  int k = blockIdx.x, d = threadIdx.x;
  float acc = 0.f;
#pragma unroll
  for (int e = 0; e < NEXP; e++)
    if (occ[k * NEXP + e]) acc += bias0[e * DM + d];
  bias_sum[k * DM + d] = acc;
}

// ---------------- combine experts + residual + LN2 ----------------
__global__ __launch_bounds__(384) void moe_combine_ln_kernel(float* __restrict__ t,
                                                             const float* __restrict__ ybuf,
                                                             const float* __restrict__ gates,
                                                             const int* __restrict__ idxb,
                                                             const float* __restrict__ bias0,
                                                             const float* __restrict__ bias_sum,
                                                             const float* __restrict__ g,
                                                             const float* __restrict__ bta,
                                                             short* __restrict__ tfh,
                                                             short* __restrict__ tfl) {
  int tok = blockIdx.x, d = threadIdx.x;
  float g0 = gates[tok * 2], g1 = gates[tok * 2 + 1];
  int i0 = idxb[tok * 2], i1 = idxb[tok * 2 + 1];
  float m0 = ybuf[(tok * 2) * DM + d] - bias0[i0 * DM + d] + bias_sum[d];
  float m1 = ybuf[(tok * 2 + 1) * DM + d] - bias0[i1 * DM + d] + bias_sum[DM + d];
  float v = t[tok * DM + d] + g0 * m0 + g1 * m1;
  float sv = v, sq = v * v;
  for (int off = 32; off > 0; off >>= 1) { sv += __shfl_xor(sv, off); sq += __shfl_xor(sq, off); }
  __shared__ float rs[6], rq[6];
  int w = d >> 6, ln = d & 63;
  if (ln == 0) { rs[w] = sv; rq[w] = sq; }
  __syncthreads();
  float mean = 0.f, ms = 0.f;
#pragma unroll
  for (int i = 0; i < 6; i++) { mean += rs[i]; ms += rq[i]; }
  mean *= (1.f / DM); ms *= (1.f / DM);
  float inv = rsqrtf(ms - mean * mean + EPSLN);
  float y = (v - mean) * inv * g[d] + bta[d];
  t[tok * DM + d] = y;
  short hs, ls; split2(y, hs, ls);
  tfh[tok * DM + d] = hs;
  tfl[tok * DM + d] = ls;
}

// ---------------- final: LN(cls) @ fc_w + fc_b ----------------
__global__ __launch_bounds__(256) void final_kernel(const float* __restrict__ t,
                                                    const float* __restrict__ ng,
                                                    const float* __restrict__ nb,
                                                    const float* __restrict__ fw,
                                                    const float* __restrict__ fb,
                                                    float* __restrict__ out) {
  int b = blockIdx.x, chunk = blockIdx.y, tid = threadIdx.x;
  __shared__ float xr[DM];
  __shared__ float rs[4], rq[4];
  const float* row = t + (b * SEQ) * DM;
  float sv = 0.f, sq = 0.f;
  for (int i = tid; i < DM; i += 256) { float x = row[i]; xr[i] = x; sv += x; sq += x * x; }
  for (int off = 32; off > 0; off >>= 1) { sv += __shfl_xor(sv, off); sq += __shfl_xor(sq, off); }
  int w = tid >> 6, ln = tid & 63;
  if (ln == 0) { rs[w] = sv; rq[w] = sq; }
  __syncthreads();
  float mean = (rs[0] + rs[1] + rs[2] + rs[3]) * (1.f / DM);
  float ms = (rq[0] + rq[1] + rq[2] + rq[3]) * (1.f / DM);
  float inv = rsqrtf(ms - mean * mean + EPSLN);
  for (int i = tid; i < DM; i += 256) xr[i] = (xr[i] - mean) * inv * ng[i] + nb[i];
  __syncthreads();
  int c = chunk * 250 + tid;
  if (tid < 250) {
    float acc = fb[c];
    for (int k = 0; k < DM; k++) acc += xr[k] * fw[k * NCLS + c];
    out[b * NCLS + c] = acc;
  }
}

extern "C" void kernel_launch(void* const* d_in, const int* in_sizes, int n_in,
                              void* d_out, int out_size, void* d_ws, size_t ws_size,
                              hipStream_t stream) {
  const float* x       = (const float*)d_in[0];
  const float* patch_w = (const float*)d_in[1];
  const float* patch_b = (const float*)d_in[2];
  const float* cls_tok = (const float*)d_in[3];
  const float* pos     = (const float*)d_in[4];
  const float* qkv_w   = (const float*)d_in[5];
  const float* qkv_b   = (const float*)d_in[6];
  const float* proj_w  = (const float*)d_in[7];
  const float* proj_b  = (const float*)d_in[8];
  const float* ln1_g   = (const float*)d_in[9];
  const float* ln1_b   = (const float*)d_in[10];
  const float* ln2_g   = (const float*)d_in[11];
  const float* ln2_b   = (const float*)d_in[12];
  const float* router_w = (const float*)d_in[13];
  const float* router_b = (const float*)d_in[14];
  const float* w1      = (const float*)d_in[15];
  const float* b1      = (const float*)d_in[16];
  const float* w2      = (const float*)d_in[17];
  const float* b2      = (const float*)d_in[18];
  const float* norm_g  = (const float*)d_in[19];
  const float* norm_b  = (const float*)d_in[20];
  const float* fc_w    = (const float*)d_in[21];
  const float* fc_b    = (const float*)d_in[22];

  float* ws = (float*)d_ws;
  float* t        = ws;                      // TOK*DM
  float* qkv      = t + TOK * DM;            // TOK*1152
  float* proj     = qkv + TOK * 1152;        // TOK*DM
  float* ybuf     = proj + TOK * DM;         // TOK*2*DM
  float* bias0    = ybuf + TOK * 2 * DM;     // NEXP*DM
  float* bias_sum = bias0 + NEXP * DM;       // 2*DM
  float* gates    = bias_sum + 2 * DM;       // TOK*2
  int* idxb   = (int*)(gates + TOK * 2);     // TOK*2
  int* lists  = idxb + TOK * 2;              // NEXP*CAPE
  int* counts = lists + NEXP * CAPE;         // NEXP
  int* occ    = counts + NEXP;               // 2*NEXP
  short* tfh = (short*)(occ + 2 * NEXP);     // TOK*DM  (16B-aligned)
  short* tfl = tfh + TOK * DM;
  short* afh = tfl + TOK * DM;
  short* afl = afh + TOK * DM;
  short* hbh = afl + TOK * DM;               // 2*TOK*HIDN
  short* hbl = hbh + 2 * TOK * HIDN;         // 2*TOK*HIDN
  short* wqf = hbl + 2 * TOK * HIDN;         // 864*1024
  short* wpf = wqf + 864 * 1024;             // 288*1024
  short* w1f = wpf + 288 * 1024;             // 8*1152*1024
  short* w2f = w1f + 8 * 1152 * 1024;        // 8*1152*1024
  short* wpatf = w2f + 8 * 1152 * 1024;      // 576*1024

  // patch embed: convert patch_w once, then MFMA GEMM with fused bias+pos
  convw_kernel<<<dim3(144, 1), 256, 0, stream>>>(patch_w, wpatf, 768, DM);
  patch_mfma_kernel<<<dim3(25, 1, 6), 256, 0, stream>>>(x, wpatf, patch_b, pos, t, tfh, tfl);
  cls_pos_kernel<<<BATCH, DM, 0, stream>>>(cls_tok, pos, t, tfh, tfl);

  for (int l = 0; l < LYR; l++) {
    convw_kernel<<<dim3(216, 1), 256, 0, stream>>>(qkv_w + (long)l * DM * 1152, wqf, DM, 1152);
    convw_kernel<<<dim3(72, 1), 256, 0, stream>>>(proj_w + (long)l * DM * DM, wpf, DM, DM);
    convw_kernel<<<dim3(288, NEXP), 256, 0, stream>>>(w1 + (long)l * NEXP * DM * HIDN, w1f, DM, HIDN);
    convw_kernel<<<dim3(288, NEXP), 256, 0, stream>>>(w2 + (long)l * NEXP * HIDN * DM, w2f, HIDN, DM);

    gemm_frag_kernel<DM, 1152, 0><<<dim3(18, 25), 256, 0, stream>>>(
        tfh, tfl, wqf, qkv_b + l * 1152, nullptr, nullptr, qkv, nullptr, nullptr);
    attn_tile_kernel<<<dim3(BATCH * NHEAD, 7), 256, 0, stream>>>(qkv, afh, afl);
    gemm_frag_kernel<DM, DM, 0><<<dim3(6, 25), 256, 0, stream>>>(
        afh, afl, wpf, proj_b + l * DM, nullptr, nullptr, proj, nullptr, nullptr);
    add_ln_kernel<<<TOK, DM, 0, stream>>>(t, proj, ln1_g + l * DM, ln1_b + l * DM, tfh, tfl);

    prep_kernel<<<NEXP, DM, 0, stream>>>(b2 + l * NEXP * DM, bias0);
    bias0_partial_kernel<<<dim3(NEXP, 12), 384, 0, stream>>>(
        b1 + l * NEXP * HIDN, w2 + (long)l * NEXP * HIDN * DM, bias0);
    unsigned kl0, kl1;
    tf2x32(0u, 42u, 0u, (unsigned)l, kl0, kl1);
    router_logits_kernel<<<TOK / 4, 256, 0, stream>>>(
        t, router_w + l * DM * NEXP, router_b + l * NEXP, kl0, kl1, gates, idxb);
    bucket_kernel<<<1, 1024, 0, stream>>>(idxb, lists, counts, occ);
    bias_sum_kernel<<<2, 384, 0, stream>>>(bias0, occ, bias_sum);
    gemm_frag_kernel<DM, HIDN, 1><<<dim3(192, 25), 256, 0, stream>>>(
        tfh, tfl, w1f, b1 + l * NEXP * HIDN, lists, counts, nullptr, hbh, hbl);
    gemm_frag_kernel<HIDN, DM, 2><<<dim3(48, 25), 256, 0, stream>>>(
        hbh, hbl, w2f, b2 + l * NEXP * DM, lists, counts, ybuf, nullptr, nullptr);
    moe_combine_ln_kernel<<<TOK, DM, 0, stream>>>(t, ybuf, gates, idxb, bias0, bias_sum,
                                                  ln2_g + l * DM, ln2_b + l * DM, tfh, tfl);
  }

  final_kernel<<<dim3(BATCH, 4), 256, 0, stream>>>(t, norm_g, norm_b, fc_w, fc_b,
                                                   (float*)d_out);
}

// Round 3
// 940.015 us; speedup vs baseline: 1.1483x; 1.1483x over previous
//
#include <hip/hip_runtime.h>
#include <hip/hip_bf16.h>

constexpr int LYR  = 4;
constexpr int DM   = 384;
constexpr int HIDN = 1536;
constexpr int NHEAD = 6;
constexpr int HDIM = 64;
constexpr int NEXP = 8;
constexpr int SEQ  = 197;
constexpr int BATCH = 8;
constexpr int TOK  = BATCH * SEQ;   // 1576
constexpr int NCLS = 1000;
constexpr int CAPE = TOK;           // max pairs per expert
constexpr int NPATCH = BATCH * 196; // 1568
constexpr float EPSLN = 1e-5f;
constexpr int KP = 40;              // LDS row pitch (bf16 elems) for patch staging

typedef __attribute__((ext_vector_type(8))) short short8v;
typedef __attribute__((ext_vector_type(4))) short short4v;
typedef __attribute__((ext_vector_type(4))) float f32x4v;

// ---------------- threefry2x32 (JAX-compatible) ----------------
__host__ __device__ inline void tf2x32(unsigned k0, unsigned k1, unsigned x0, unsigned x1,
                                       unsigned& y0, unsigned& y1) {
  unsigned ks2 = k0 ^ k1 ^ 0x1BD11BDAu;
  unsigned v0 = x0 + k0, v1 = x1 + k1;
#define TFR(r) { v0 += v1; v1 = (v1 << (r)) | (v1 >> (32 - (r))); v1 ^= v0; }
  TFR(13) TFR(15) TFR(26) TFR(6)
  v0 += k1;  v1 += ks2 + 1u;
  TFR(17) TFR(29) TFR(16) TFR(24)
  v0 += ks2; v1 += k0 + 2u;
  TFR(13) TFR(15) TFR(26) TFR(6)
  v0 += k0;  v1 += k1 + 3u;
  TFR(17) TFR(29) TFR(16) TFR(24)
  v0 += k1;  v1 += ks2 + 4u;
  TFR(13) TFR(15) TFR(26) TFR(6)
  v0 += ks2; v1 += k0 + 5u;
#undef TFR
  y0 = v0; y1 = v1;
}

// XLA ErfInv32 (Giles) — matches jax.lax.erf_inv for f32
__device__ inline float erfinv32(float x) {
  float w = -log1pf(-x * x);
  float p;
  if (w < 5.f) {
    w -= 2.5f;
    p = 2.81022636e-08f;
    p = fmaf(p, w, 3.43273939e-07f);
    p = fmaf(p, w, -3.5233877e-06f);
    p = fmaf(p, w, -4.39150654e-06f);
    p = fmaf(p, w, 0.00021858087f);
    p = fmaf(p, w, -0.00125372503f);
    p = fmaf(p, w, -0.00417768164f);
    p = fmaf(p, w, 0.246640727f);
    p = fmaf(p, w, 1.50140941f);
  } else {
    w = sqrtf(w) - 3.f;
    p = -0.000200214257f;
    p = fmaf(p, w, 0.000100950558f);
    p = fmaf(p, w, 0.00134934322f);
    p = fmaf(p, w, -0.00367342844f);
    p = fmaf(p, w, 0.00573950773f);
    p = fmaf(p, w, -0.0076224613f);
    p = fmaf(p, w, 0.00943887047f);
    p = fmaf(p, w, 1.00167406f);
    p = fmaf(p, w, 2.83297682f);
  }
  return p * x;
}

__device__ inline float gelu_f(float x) {
  return 0.5f * x * (1.f + erff(x * 0.70710678118654752f));
}

__device__ inline unsigned short bf16_rne(float x) {
  unsigned u = __float_as_uint(x);
  unsigned r = (u + 0x7fffu + ((u >> 16) & 1u)) >> 16;
  return (unsigned short)r;
}
__device__ inline void split2(float x, short& hs, short& ls) {
  unsigned hu = bf16_rne(x);
  float hf = __uint_as_float(hu << 16);
  unsigned lu = bf16_rne(x - hf);
  hs = (short)hu; ls = (short)lu;
}

// =====================================================================
// Weight pre-conversion: W[K][N] fp32 -> MFMA A-frag chunks, hi/lo bf16.
// =====================================================================
__global__ __launch_bounds__(256) void convw_kernel(const float* __restrict__ src,
                                                    short* __restrict__ dst,
                                                    int K, int N) {
  const int nchunks = (K >> 5) * (N >> 4);
  const int chunk = blockIdx.x * 4 + (threadIdx.x >> 6);
  if (chunk >= nchunks) return;
  const int lane = threadIdx.x & 63;
  const long eoffS = (long)blockIdx.y * K * N;
  const long eoffD = (long)blockIdx.y * nchunks * 1024;
  const int nc = N >> 4;
  const int kt = chunk / nc, nt = chunk - kt * nc;
  const int n = nt * 16 + (lane & 15);
  const int kb = kt * 32 + (lane >> 4) * 8;
  short8v hv, lv;
#pragma unroll
  for (int j = 0; j < 8; j++) {
    short h, l;
    split2(src[eoffS + (long)(kb + j) * N + n], h, l);
    hv[j] = h; lv[j] = l;
  }
  *(short8v*)&dst[eoffD + (long)chunk * 1024 + lane * 8] = hv;
  *(short8v*)&dst[eoffD + (long)chunk * 1024 + 512 + lane * 8] = lv;
}

// =====================================================================
// MFMA GEMM, LDS double-buffered, pre-split A (Ah/Al row-major [row][K]).
// One barrier per K-step; A+W prefetched into regs before the barrier.
// MODE: 0 dense, 1 moe1 (gelu -> bf16 split out), 2 moe2.
// Grid: (strips, m_tiles), strip fast-dim, strips % 8 == 0 (padded) so
// all M-blocks of a W-strip land on one XCD (ids differ by multiples of 8).
// =====================================================================
template <int KTOT, int NTOT, int MODE>
__global__ __launch_bounds__(256) void gemm_lds_kernel(
    const short* __restrict__ Ah, const short* __restrict__ Al,
    const short* __restrict__ Wf, const float* __restrict__ bias,
    const int* __restrict__ lists, const int* __restrict__ counts,
    float* __restrict__ outF, short* __restrict__ outH, short* __restrict__ outL) {
  constexpr int SPE = NTOT / 64;   // strips per expert
  constexpr int NK = KTOT / 32;
  constexpr int PIT = 36;          // LDS pitch (shorts): 72B stride, conflict-friendly
  const int strip = blockIdx.x;
  int e, c0;
  if (MODE) { e = strip / SPE; c0 = (strip - e * SPE) * 64; }
  else { e = 0; c0 = strip * 64; if (c0 >= NTOT) return; }
  const int m = blockIdx.y;
  const int cnt = MODE ? counts[e] : TOK;
  if (m * 64 >= cnt) return;
  const int rowsM = min(64, cnt - m * 64);
  __shared__ int ent[64];
  __shared__ short sh[2][64 * PIT];
  __shared__ short sl[2][64 * PIT];
  const int tid = threadIdx.x;
  const int w = tid >> 6, lane = tid & 63;
  if (MODE) {
    if (tid < 64) ent[tid] = (tid < rowsM) ? lists[e * CAPE + m * 64 + tid] : -1;
    __syncthreads();
  }
  const int sr = tid >> 2, skq = (tid & 3) * 8;
  bool okr; long arow = 0;
  if (MODE == 0) {
    okr = (sr < rowsM);
    arow = (long)(m * 64 + (okr ? sr : 0)) * KTOT;
  } else {
    const int pid = ent[sr];
    okr = (pid >= 0);
    arow = (long)(okr ? ((MODE == 1) ? (pid >> 1) : pid) : 0) * KTOT;
  }
  const short* W = Wf + (long)e * ((KTOT >> 5) * (NTOT >> 4)) * 1024;
  const int wm = (w >> 1) * 32, wn = (w & 1) * 32;
  f32x4v Cr[2][2] = {};
  short8v ch, cl;
#pragma unroll
  for (int j = 0; j < 8; j++) { ch[j] = 0; cl[j] = 0; }
  if (okr) {
    ch = *(const short8v*)&Ah[arow + skq];
    cl = *(const short8v*)&Al[arow + skq];
  }
#pragma unroll 2
  for (int kt = 0; kt < NK; ++kt) {
    const int cb = kt & 1;
    *(short8v*)&sh[cb][sr * PIT + skq] = ch;
    *(short8v*)&sl[cb][sr * PIT + skq] = cl;
    if (kt + 1 < NK && okr) {
      ch = *(const short8v*)&Ah[arow + (kt + 1) * 32 + skq];
      cl = *(const short8v*)&Al[arow + (kt + 1) * 32 + skq];
    }
    const long wkb = ((long)kt * (NTOT >> 4) + (c0 >> 4) + (wn >> 4)) * 1024;
    short8v wh[2], wl[2];
#pragma unroll
    for (int nt = 0; nt < 2; ++nt) {
      wh[nt] = *(const short8v*)&W[wkb + nt * 1024 + lane * 8];
      wl[nt] = *(const short8v*)&W[wkb + nt * 1024 + 512 + lane * 8];
    }
    __syncthreads();
    short8v bh[2], bl[2];
#pragma unroll
    for (int tt = 0; tt < 2; ++tt) {
      const int trow = wm + tt * 16 + (lane & 15);
      bh[tt] = *(const short8v*)&sh[cb][trow * PIT + (lane >> 4) * 8];
      bl[tt] = *(const short8v*)&sl[cb][trow * PIT + (lane >> 4) * 8];
    }
#pragma unroll
    for (int nt = 0; nt < 2; ++nt) {
#pragma unroll
      for (int tt = 0; tt < 2; ++tt) {
        Cr[tt][nt] = __builtin_amdgcn_mfma_f32_16x16x32_bf16(wh[nt], bh[tt], Cr[tt][nt], 0, 0, 0);
        Cr[tt][nt] = __builtin_amdgcn_mfma_f32_16x16x32_bf16(wh[nt], bl[tt], Cr[tt][nt], 0, 0, 0);
        Cr[tt][nt] = __builtin_amdgcn_mfma_f32_16x16x32_bf16(wl[nt], bh[tt], Cr[tt][nt], 0, 0, 0);
      }
    }
  }
  const int tl = lane & 15;
  const int nq = (lane >> 4) * 4;
#pragma unroll
  for (int tt = 0; tt < 2; ++tt) {
    const int trow = wm + tt * 16 + tl;
    if (trow < rowsM) {
      const long orow = (long)(MODE ? ent[trow] : (m * 64 + trow)) * NTOT;
#pragma unroll
      for (int nt = 0; nt < 2; ++nt) {
        const int n = c0 + wn + nt * 16 + nq;
        const float4 bv = *(const float4*)&bias[(MODE ? e * NTOT : 0) + n];
        float o0 = Cr[tt][nt][0] + bv.x, o1 = Cr[tt][nt][1] + bv.y;
        float o2 = Cr[tt][nt][2] + bv.z, o3 = Cr[tt][nt][3] + bv.w;
        if (MODE == 1) {
          o0 = gelu_f(o0); o1 = gelu_f(o1); o2 = gelu_f(o2); o3 = gelu_f(o3);
          short4v hv, lv; short hs, ls;
          split2(o0, hs, ls); hv[0] = hs; lv[0] = ls;
          split2(o1, hs, ls); hv[1] = hs; lv[1] = ls;
          split2(o2, hs, ls); hv[2] = hs; lv[2] = ls;
          split2(o3, hs, ls); hv[3] = hs; lv[3] = ls;
          *(short4v*)&outH[orow + n] = hv;
          *(short4v*)&outL[orow + n] = lv;
        } else {
          *(float4*)&outF[orow + n] = make_float4(o0, o1, o2, o3);
        }
      }
    }
  }
}

// =====================================================================
// Patch embed as MFMA GEMM (gathers A from x via unfold geometry).
// Epilogue fuses patch_b + pos, writes t fp32 + tfh/tfl bf16 mirrors.
// =====================================================================
__global__ __launch_bounds__(256) void patch_mfma_kernel(const float* __restrict__ x,
                                                         const short* __restrict__ Wf,
                                                         const float* __restrict__ pb,
                                                         const float* __restrict__ pos,
                                                         float* __restrict__ t,
                                                         short* __restrict__ tfh,
                                                         short* __restrict__ tfl) {
  constexpr int KTOT = 768, NTOT = DM;
  const int rowsM = min(64, NPATCH - (int)blockIdx.x * 64);
  const int c0 = blockIdx.z * 64;
  const int tid = threadIdx.x;
  const int w = tid >> 6, lane = tid & 63;
  __shared__ short xh[64 * KP];
  __shared__ short xl[64 * KP];
  const int sr = tid >> 2, skq = (tid & 3) * 8;
  const bool okr = (sr < rowsM);
  const int p = blockIdx.x * 64 + sr;
  const int pbat = okr ? (p / 196) : 0;
  const int pn = okr ? (p - pbat * 196) : 0;
  const int hp = pn / 14, wp = pn - hp * 14;
  const float* xbase = x + ((long)pbat * 3 * 224 + hp * 16) * 224 + wp * 16;
  const int wm = (w >> 1) * 32, wn = (w & 1) * 32;
  f32x4v Cr[2][2] = {};
  float4 ra = make_float4(0.f, 0.f, 0.f, 0.f), rb = ra;
  if (okr) {
    const int f = skq;  // kt = 0
    const int c = f >> 8, py = (f >> 4) & 15, px = f & 15;
    const float* ptr = xbase + ((long)c * 224 + py) * 224 + px;
    ra = *(const float4*)ptr;
    rb = *(const float4*)(ptr + 4);
  }
  for (int kt = 0; kt < KTOT / 32; ++kt) {
    __syncthreads();
    {
      const float v[8] = {ra.x, ra.y, ra.z, ra.w, rb.x, rb.y, rb.z, rb.w};
      short8v hv, lv;
#pragma unroll
      for (int j = 0; j < 8; j++) { short h, l; split2(v[j], h, l); hv[j] = h; lv[j] = l; }
      *(short8v*)&xh[sr * KP + skq] = hv;
      *(short8v*)&xl[sr * KP + skq] = lv;
    }
    if (kt + 1 < KTOT / 32 && okr) {
      const int f = (kt + 1) * 32 + skq;
      const int c = f >> 8, py = (f >> 4) & 15, px = f & 15;
      const float* ptr = xbase + ((long)c * 224 + py) * 224 + px;
      ra = *(const float4*)ptr;
      rb = *(const float4*)(ptr + 4);
    }
    __syncthreads();
    short8v bhv[2], blv[2];
#pragma unroll
    for (int tt = 0; tt < 2; ++tt) {
      const int trow = wm + tt * 16 + (lane & 15);
      bhv[tt] = *(const short8v*)&xh[trow * KP + (lane >> 4) * 8];
      blv[tt] = *(const short8v*)&xl[trow * KP + (lane >> 4) * 8];
    }
    const long wkb = ((long)kt * (NTOT >> 4) + (c0 >> 4) + (wn >> 4)) * 1024;
#pragma unroll
    for (int nt = 0; nt < 2; ++nt) {
      const short8v wh = *(const short8v*)&Wf[wkb + nt * 1024 + lane * 8];
      const short8v wl = *(const short8v*)&Wf[wkb + nt * 1024 + 512 + lane * 8];
#pragma unroll
      for (int tt = 0; tt < 2; ++tt) {
        Cr[tt][nt] = __builtin_amdgcn_mfma_f32_16x16x32_bf16(wh, bhv[tt], Cr[tt][nt], 0, 0, 0);
        Cr[tt][nt] = __builtin_amdgcn_mfma_f32_16x16x32_bf16(wh, blv[tt], Cr[tt][nt], 0, 0, 0);
        Cr[tt][nt] = __builtin_amdgcn_mfma_f32_16x16x32_bf16(wl, bhv[tt], Cr[tt][nt], 0, 0, 0);
      }
    }
  }
  const int tl = lane & 15;
  const int nq = (lane >> 4) * 4;
#pragma unroll
  for (int tt = 0; tt < 2; ++tt) {
    const int trow = wm + tt * 16 + tl;
    if (trow < rowsM) {
      const int r = blockIdx.x * 64 + trow;
      const int b2 = r / 196, n2 = r - b2 * 196;
      const long orow = (long)(b2 * SEQ + 1 + n2) * DM;
#pragma unroll
      for (int nt = 0; nt < 2; ++nt) {
        const int n = c0 + wn + nt * 16 + nq;
        const float4 bv = *(const float4*)&pb[n];
        const float4 pv = *(const float4*)&pos[(1 + n2) * DM + n];
        float o0 = Cr[tt][nt][0] + bv.x + pv.x;
        float o1 = Cr[tt][nt][1] + bv.y + pv.y;
        float o2 = Cr[tt][nt][2] + bv.z + pv.z;
        float o3 = Cr[tt][nt][3] + bv.w + pv.w;
        *(float4*)&t[orow + n] = make_float4(o0, o1, o2, o3);
        short4v hv, lv; short hs, ls;
        split2(o0, hs, ls); hv[0] = hs; lv[0] = ls;
        split2(o1, hs, ls); hv[1] = hs; lv[1] = ls;
        split2(o2, hs, ls); hv[2] = hs; lv[2] = ls;
        split2(o3, hs, ls); hv[3] = hs; lv[3] = ls;
        *(short4v*)&tfh[orow + n] = hv;
        *(short4v*)&tfl[orow + n] = lv;
      }
    }
  }
}

__global__ void cls_pos_kernel(const float* __restrict__ cls, const float* __restrict__ pos,
                               float* __restrict__ t,
                               short* __restrict__ tfh, short* __restrict__ tfl) {
  int b = blockIdx.x, d = threadIdx.x;
  float v = cls[d] + pos[d];
  t[(b * SEQ) * DM + d] = v;
  short hs, ls; split2(v, hs, ls);
  tfh[(b * SEQ) * DM + d] = hs;
  tfl[(b * SEQ) * DM + d] = ls;
}

// =====================================================================
// Tiled attention: one block per (b, h, 32-query tile). Two-pass softmax.
// Output written as bf16 hi/lo split (feeds proj GEMM directly).
// =====================================================================
constexpr int QT = 32;   // queries per block
constexpr int SP = 208;  // S row pitch
__global__ __launch_bounds__(256) void attn_tile_kernel(const float* __restrict__ qkv,
                                                        short* __restrict__ afh,
                                                        short* __restrict__ afl) {
  const int bh = blockIdx.x;
  const int b = bh / NHEAD, h = bh % NHEAD;
  const int q0 = blockIdx.y * QT;
  const int nq = min(QT, SEQ - q0);
  __shared__ float Qs[64][QT + 4];   // d-major
  __shared__ float KV[64][68];       // phase1: KT[d][key]; phase3: Vs[key][d]
  __shared__ float Ss[QT][SP];
  const int tid = threadIdx.x;
  const int tx = tid & 15, ty = tid >> 4;
  for (int i = tid; i < QT * 16; i += 256) {
    const int q = i >> 4, dq = (i & 15) << 2;
    float4 v = make_float4(0.f, 0.f, 0.f, 0.f);
    if (q < nq) v = *(const float4*)&qkv[(long)(b * SEQ + q0 + q) * 1152 + h * HDIM + dq];
    Qs[dq + 0][q] = v.x; Qs[dq + 1][q] = v.y; Qs[dq + 2][q] = v.z; Qs[dq + 3][q] = v.w;
  }
  // ---- phase 1: scores ----
  for (int kt = 0; kt < 4; ++kt) {
    const int kbase = kt * 64;
    __syncthreads();
    for (int i = tid; i < 64 * 16; i += 256) {
      const int key = i >> 4, dq = (i & 15) << 2;
      float4 v = make_float4(0.f, 0.f, 0.f, 0.f);
      if (kbase + key < SEQ)
        v = *(const float4*)&qkv[(long)(b * SEQ + kbase + key) * 1152 + DM + h * HDIM + dq];
      KV[dq + 0][key] = v.x; KV[dq + 1][key] = v.y; KV[dq + 2][key] = v.z; KV[dq + 3][key] = v.w;
    }
    __syncthreads();
    float acc[2][4] = {};
#pragma unroll 16
    for (int d = 0; d < 64; ++d) {
      const float4 k4 = *(const float4*)&KV[d][tx << 2];
      const float a0 = Qs[d][ty * 2], a1 = Qs[d][ty * 2 + 1];
      const float kk[4] = {k4.x, k4.y, k4.z, k4.w};
#pragma unroll
      for (int j = 0; j < 4; j++) {
        acc[0][j] = fmaf(a0, kk[j], acc[0][j]);
        acc[1][j] = fmaf(a1, kk[j], acc[1][j]);
      }
    }
#pragma unroll
    for (int i = 0; i < 2; i++) {
      float4 o = make_float4(acc[i][0] * 0.125f, acc[i][1] * 0.125f,
                             acc[i][2] * 0.125f, acc[i][3] * 0.125f);
      *(float4*)&Ss[ty * 2 + i][kbase + (tx << 2)] = o;
    }
  }
  __syncthreads();
  // ---- phase 2: softmax per row (8 lanes/row) ----
  {
    const int row = tid >> 3, c = tid & 7;
    float m = -1e30f;
    for (int k = c; k < SEQ; k += 8) m = fmaxf(m, Ss[row][k]);
    m = fmaxf(m, __shfl_xor(m, 1)); m = fmaxf(m, __shfl_xor(m, 2)); m = fmaxf(m, __shfl_xor(m, 4));
    float s = 0.f;
    for (int k = c; k < SEQ; k += 8) { float e2 = __expf(Ss[row][k] - m); Ss[row][k] = e2; s += e2; }
    s += __shfl_xor(s, 1); s += __shfl_xor(s, 2); s += __shfl_xor(s, 4);
    const float inv = 1.f / s;
    for (int k = c; k < SEQ; k += 8) Ss[row][k] *= inv;
  }
  // ---- phase 3: O = P@V ----
  float acc[2][4] = {};
  for (int kt = 0; kt < 4; ++kt) {
    const int kbase = kt * 64;
    const int kend = min(64, SEQ - kbase);
    __syncthreads();
    for (int i = tid; i < 64 * 16; i += 256) {
      const int key = i >> 4, dq = (i & 15) << 2;
      float4 v = make_float4(0.f, 0.f, 0.f, 0.f);
      if (kbase + key < SEQ)
        v = *(const float4*)&qkv[(long)(b * SEQ + kbase + key) * 1152 + 2 * DM + h * HDIM + dq];
      *(float4*)&KV[key][dq] = v;
    }
    __syncthreads();
    for (int k = 0; k < kend; ++k) {
      const float4 v4 = *(const float4*)&KV[k][tx << 2];
      const float p0 = Ss[ty * 2][kbase + k], p1 = Ss[ty * 2 + 1][kbase + k];
      const float vv[4] = {v4.x, v4.y, v4.z, v4.w};
#pragma unroll
      for (int j = 0; j < 4; j++) {
        acc[0][j] = fmaf(p0, vv[j], acc[0][j]);
        acc[1][j] = fmaf(p1, vv[j], acc[1][j]);
      }
    }
  }
#pragma unroll
  for (int i = 0; i < 2; i++) {
    const int row = ty * 2 + i;
    if (row < nq) {
      const long o = (long)(b * SEQ + q0 + row) * DM + h * HDIM + (tx << 2);
      short4v hv, lv; short hs, ls;
      split2(acc[i][0], hs, ls); hv[0] = hs; lv[0] = ls;
      split2(acc[i][1], hs, ls); hv[1] = hs; lv[1] = ls;
      split2(acc[i][2], hs, ls); hv[2] = hs; lv[2] = ls;
      split2(acc[i][3], hs, ls); hv[3] = hs; lv[3] = ls;
      *(short4v*)&afh[o] = hv;
      *(short4v*)&afl[o] = lv;
    }
  }
}

// ---------------- residual add + LayerNorm (per token) ----------------
__global__ __launch_bounds__(384) void add_ln_kernel(float* __restrict__ t,
                                                     const float* __restrict__ delta,
                                                     const float* __restrict__ g,
                                                     const float* __restrict__ bta,
                                                     short* __restrict__ tfh,
                                                     short* __restrict__ tfl) {
  int tok = blockIdx.x, d = threadIdx.x;
  float v = t[tok * DM + d] + delta[tok * DM + d];
  float sv = v, sq = v * v;
  for (int off = 32; off > 0; off >>= 1) { sv += __shfl_xor(sv, off); sq += __shfl_xor(sq, off); }
  __shared__ float rs[6], rq[6];
  int w = d >> 6, ln = d & 63;
  if (ln == 0) { rs[w] = sv; rq[w] = sq; }
  __syncthreads();
  float mean = 0.f, ms = 0.f;
#pragma unroll
  for (int i = 0; i < 6; i++) { mean += rs[i]; ms += rq[i]; }
  mean *= (1.f / DM); ms *= (1.f / DM);
  float inv = rsqrtf(ms - mean * mean + EPSLN);
  float y = (v - mean) * inv * g[d] + bta[d];
  t[tok * DM + d] = y;
  short hs, ls; split2(y, hs, ls);
  tfh[tok * DM + d] = hs;
  tfl[tok * DM + d] = ls;
}

// ---------------- router logits + top-2 (no global atomics) ----------------
__global__ __launch_bounds__(256) void router_logits_kernel(const float* __restrict__ t,
                                                            const float* __restrict__ rw,
                                                            const float* __restrict__ rb,
                                                            unsigned k0, unsigned k1,
                                                            float* __restrict__ gates,
                                                            int* __restrict__ idxb) {
  const int tok = blockIdx.x * 4 + (threadIdx.x >> 6);
  const int lane = threadIdx.x & 63;
  const int e = lane & 7, j = lane >> 3;
  const float* xr = t + tok * DM;
  float acc = 0.f;
  for (int d2 = j * 48; d2 < j * 48 + 48; d2++) acc += xr[d2] * rw[d2 * NEXP + e];
  acc += __shfl_xor(acc, 8);
  acc += __shfl_xor(acc, 16);
  acc += __shfl_xor(acc, 32);
  if (lane < 8) {
    acc += rb[e];
    unsigned i = (unsigned)(tok * NEXP + e);
    unsigned y0, y1;
    tf2x32(k0, k1, 0u, i, y0, y1);
    unsigned bits = y0 ^ y1;
    float f = __uint_as_float(0x3f800000u | (bits >> 9)) - 1.0f;
    const float lo = -0.99999994f;
    float u = f * 2.0f + lo;
    u = fmaxf(lo, u);
    acc += 0.01f * (1.41421356f * erfinv32(u));
  }
  float lg[8];
#pragma unroll
  for (int qq = 0; qq < 8; qq++) lg[qq] = __shfl(acc, qq);
  if (lane == 0) {
    int i0 = 0; float v0 = lg[0];
#pragma unroll
    for (int qq = 1; qq < 8; qq++) if (lg[qq] > v0) { v0 = lg[qq]; i0 = qq; }
    int i1 = -1; float v1 = -1e30f;
#pragma unroll
    for (int qq = 0; qq < 8; qq++) if (qq != i0 && lg[qq] > v1) { v1 = lg[qq]; i1 = qq; }
    float e1 = __expf(v1 - v0);
    float g0 = 1.f / (1.f + e1);
    idxb[tok * 2] = i0; idxb[tok * 2 + 1] = i1;
    gates[tok * 2] = g0; gates[tok * 2 + 1] = 1.f - g0;
  }
}

// ---------------- bucket: single block bins all pairs via LDS atomics ----------------
__global__ __launch_bounds__(1024) void bucket_kernel(const int* __restrict__ idxb,
                                                      int* __restrict__ lists,
                                                      int* __restrict__ counts,
                                                      int* __restrict__ occ) {
  __shared__ int lc[NEXP];
  __shared__ int locc[2 * NEXP];
  const int tid = threadIdx.x;
  if (tid < NEXP) lc[tid] = 0;
  if (tid < 2 * NEXP) locc[tid] = 0;
  __syncthreads();
  for (int i = tid; i < 2 * TOK; i += 1024) {
    const int e = idxb[i];
    const int p = atomicAdd(&lc[e], 1);
    lists[e * CAPE + p] = i;
    locc[(i & 1) * NEXP + e] = 1;
  }
  __syncthreads();
  if (tid < NEXP) counts[tid] = lc[tid];
  if (tid < 2 * NEXP) occ[tid] = locc[tid];
}

// ---------------- prep: bias0 = b2 ----------------
__global__ void prep_kernel(const float* __restrict__ b2, float* __restrict__ bias0) {
  int e = blockIdx.x, c = threadIdx.x;
  bias0[e * DM + c] = b2[e * DM + c];
}

// ---------------- bias0 += gelu(b1)@W2 partial over K-chunks ----------------
__global__ __launch_bounds__(384) void bias0_partial_kernel(const float* __restrict__ b1,
                                                            const float* __restrict__ w2,
                                                            float* __restrict__ bias0) {
  const int e = blockIdx.x, kc = blockIdx.y;
  __shared__ float gb[128];
  const int tid = threadIdx.x;
  if (tid < 128) gb[tid] = gelu_f(b1[e * HIDN + kc * 128 + tid]);
  __syncthreads();
  float acc = 0.f;
  const float* W = w2 + ((long)e * HIDN + kc * 128) * DM + tid;
  for (int j2 = 0; j2 < 128; j2++) acc += gb[j2] * W[(long)j2 * DM];
  atomicAdd(&bias0[e * DM + tid], acc);
}

__global__ __launch_bounds__(384) void bias_sum_kernel(const float* __restrict__ bias0,
                                                       const int* __restrict__ occ,
                                                       float* __restrict__ bias_sum) {
  int k = blockIdx.x, d = threadIdx.x;
  float acc = 0.f;
#pragma unroll
  for (int e = 0; e < NEXP; e++)
    if (occ[k * NEXP + e]) acc += bias0[e * DM + d];
  bias_sum[k * DM + d] = acc;
}

// ---------------- combine experts + residual + LN2 ----------------
__global__ __launch_bounds__(384) void moe_combine_ln_kernel(float* __restrict__ t,
                                                             const float* __restrict__ ybuf,
                                                             const float* __restrict__ gates,
                                                             const int* __restrict__ idxb,
                                                             const float* __restrict__ bias0,
                                                             const float* __restrict__ bias_sum,
                                                             const float* __restrict__ g,
                                                             const float* __restrict__ bta,
                                                             short* __restrict__ tfh,
                                                             short* __restrict__ tfl) {
  int tok = blockIdx.x, d = threadIdx.x;
  float g0 = gates[tok * 2], g1 = gates[tok * 2 + 1];
  int i0 = idxb[tok * 2], i1 = idxb[tok * 2 + 1];
  float m0 = ybuf[(tok * 2) * DM + d] - bias0[i0 * DM + d] + bias_sum[d];
  float m1 = ybuf[(tok * 2 + 1) * DM + d] - bias0[i1 * DM + d] + bias_sum[DM + d];
  float v = t[tok * DM + d] + g0 * m0 + g1 * m1;
  float sv = v, sq = v * v;
  for (int off = 32; off > 0; off >>= 1) { sv += __shfl_xor(sv, off); sq += __shfl_xor(sq, off); }
  __shared__ float rs[6], rq[6];
  int w = d >> 6, ln = d & 63;
  if (ln == 0) { rs[w] = sv; rq[w] = sq; }
  __syncthreads();
  float mean = 0.f, ms = 0.f;
#pragma unroll
  for (int i = 0; i < 6; i++) { mean += rs[i]; ms += rq[i]; }
  mean *= (1.f / DM); ms *= (1.f / DM);
  float inv = rsqrtf(ms - mean * mean + EPSLN);
  float y = (v - mean) * inv * g[d] + bta[d];
  t[tok * DM + d] = y;
  short hs, ls; split2(y, hs, ls);
  tfh[tok * DM + d] = hs;
  tfl[tok * DM + d] = ls;
}

// ---------------- final: LN(cls) @ fc_w + fc_b ----------------
__global__ __launch_bounds__(256) void final_kernel(const float* __restrict__ t,
                                                    const float* __restrict__ ng,
                                                    const float* __restrict__ nb,
                                                    const float* __restrict__ fw,
                                                    const float* __restrict__ fb,
                                                    float* __restrict__ out) {
  int b = blockIdx.x, chunk = blockIdx.y, tid = threadIdx.x;
  __shared__ float xr[DM];
  __shared__ float rs[4], rq[4];
  const float* row = t + (b * SEQ) * DM;
  float sv = 0.f, sq = 0.f;
  for (int i = tid; i < DM; i += 256) { float x = row[i]; xr[i] = x; sv += x; sq += x * x; }
  for (int off = 32; off > 0; off >>= 1) { sv += __shfl_xor(sv, off); sq += __shfl_xor(sq, off); }
  int w = tid >> 6, ln = tid & 63;
  if (ln == 0) { rs[w] = sv; rq[w] = sq; }
  __syncthreads();
  float mean = (rs[0] + rs[1] + rs[2] + rs[3]) * (1.f / DM);
  float ms = (rq[0] + rq[1] + rq[2] + rq[3]) * (1.f / DM);
  float inv = rsqrtf(ms - mean * mean + EPSLN);
  for (int i = tid; i < DM; i += 256) xr[i] = (xr[i] - mean) * inv * ng[i] + nb[i];
  __syncthreads();
  int c = chunk * 250 + tid;
  if (tid < 250) {
    float acc = fb[c];
    for (int k = 0; k < DM; k++) acc += xr[k] * fw[k * NCLS + c];
    out[b * NCLS + c] = acc;
  }
}

extern "C" void kernel_launch(void* const* d_in, const int* in_sizes, int n_in,
                              void* d_out, int out_size, void* d_ws, size_t ws_size,
                              hipStream_t stream) {
  const float* x       = (const float*)d_in[0];
  const float* patch_w = (const float*)d_in[1];
  const float* patch_b = (const float*)d_in[2];
  const float* cls_tok = (const float*)d_in[3];
  const float* pos     = (const float*)d_in[4];
  const float* qkv_w   = (const float*)d_in[5];
  const float* qkv_b   = (const float*)d_in[6];
  const float* proj_w  = (const float*)d_in[7];
  const float* proj_b  = (const float*)d_in[8];
  const float* ln1_g   = (const float*)d_in[9];
  const float* ln1_b   = (const float*)d_in[10];
  const float* ln2_g   = (const float*)d_in[11];
  const float* ln2_b   = (const float*)d_in[12];
  const float* router_w = (const float*)d_in[13];
  const float* router_b = (const float*)d_in[14];
  const float* w1      = (const float*)d_in[15];
  const float* b1      = (const float*)d_in[16];
  const float* w2      = (const float*)d_in[17];
  const float* b2      = (const float*)d_in[18];
  const float* norm_g  = (const float*)d_in[19];
  const float* norm_b  = (const float*)d_in[20];
  const float* fc_w    = (const float*)d_in[21];
  const float* fc_b    = (const float*)d_in[22];

  float* ws = (float*)d_ws;
  float* t        = ws;                      // TOK*DM
  float* qkv      = t + TOK * DM;            // TOK*1152
  float* proj     = qkv + TOK * 1152;        // TOK*DM
  float* ybuf     = proj + TOK * DM;         // TOK*2*DM
  float* bias0    = ybuf + TOK * 2 * DM;     // NEXP*DM
  float* bias_sum = bias0 + NEXP * DM;       // 2*DM
  float* gates    = bias_sum + 2 * DM;       // TOK*2
  int* idxb   = (int*)(gates + TOK * 2);     // TOK*2
  int* lists  = idxb + TOK * 2;              // NEXP*CAPE
  int* counts = lists + NEXP * CAPE;         // NEXP
  int* occ    = counts + NEXP;               // 2*NEXP
  short* tfh = (short*)(occ + 2 * NEXP);     // TOK*DM  (16B-aligned)
  short* tfl = tfh + TOK * DM;
  short* afh = tfl + TOK * DM;
  short* afl = afh + TOK * DM;
  short* hbh = afl + TOK * DM;               // 2*TOK*HIDN
  short* hbl = hbh + 2 * TOK * HIDN;         // 2*TOK*HIDN
  short* wqf = hbl + 2 * TOK * HIDN;         // 864*1024
  short* wpf = wqf + 864 * 1024;             // 288*1024
  short* w1f = wpf + 288 * 1024;             // 8*1152*1024
  short* w2f = w1f + 8 * 1152 * 1024;        // 8*1152*1024
  short* wpatf = w2f + 8 * 1152 * 1024;      // 576*1024

  // patch embed: convert patch_w once, then MFMA GEMM with fused bias+pos
  convw_kernel<<<dim3(144, 1), 256, 0, stream>>>(patch_w, wpatf, 768, DM);
  patch_mfma_kernel<<<dim3(25, 1, 6), 256, 0, stream>>>(x, wpatf, patch_b, pos, t, tfh, tfl);
  cls_pos_kernel<<<BATCH, DM, 0, stream>>>(cls_tok, pos, t, tfh, tfl);

  for (int l = 0; l < LYR; l++) {
    convw_kernel<<<dim3(216, 1), 256, 0, stream>>>(qkv_w + (long)l * DM * 1152, wqf, DM, 1152);
    convw_kernel<<<dim3(72, 1), 256, 0, stream>>>(proj_w + (long)l * DM * DM, wpf, DM, DM);
    convw_kernel<<<dim3(288, NEXP), 256, 0, stream>>>(w1 + (long)l * NEXP * DM * HIDN, w1f, DM, HIDN);
    convw_kernel<<<dim3(288, NEXP), 256, 0, stream>>>(w2 + (long)l * NEXP * HIDN * DM, w2f, HIDN, DM);

    gemm_lds_kernel<DM, 1152, 0><<<dim3(24, 25), 256, 0, stream>>>(
        tfh, tfl, wqf, qkv_b + l * 1152, nullptr, nullptr, qkv, nullptr, nullptr);
    attn_tile_kernel<<<dim3(BATCH * NHEAD, 7), 256, 0, stream>>>(qkv, afh, afl);
    gemm_lds_kernel<DM, DM, 0><<<dim3(8, 25), 256, 0, stream>>>(
        afh, afl, wpf, proj_b + l * DM, nullptr, nullptr, proj, nullptr, nullptr);
    add_ln_kernel<<<TOK, DM, 0, stream>>>(t, proj, ln1_g + l * DM, ln1_b + l * DM, tfh, tfl);

    prep_kernel<<<NEXP, DM, 0, stream>>>(b2 + l * NEXP * DM, bias0);
    bias0_partial_kernel<<<dim3(NEXP, 12), 384, 0, stream>>>(
        b1 + l * NEXP * HIDN, w2 + (long)l * NEXP * HIDN * DM, bias0);
    unsigned kl0, kl1;
    tf2x32(0u, 42u, 0u, (unsigned)l, kl0, kl1);
    router_logits_kernel<<<TOK / 4, 256, 0, stream>>>(
        t, router_w + l * DM * NEXP, router_b + l * NEXP, kl0, kl1, gates, idxb);
    bucket_kernel<<<1, 1024, 0, stream>>>(idxb, lists, counts, occ);
    bias_sum_kernel<<<2, 384, 0, stream>>>(bias0, occ, bias_sum);
    gemm_lds_kernel<DM, HIDN, 1><<<dim3(192, 25), 256, 0, stream>>>(
        tfh, tfl, w1f, b1 + l * NEXP * HIDN, lists, counts, nullptr, hbh, hbl);
    gemm_lds_kernel<HIDN, DM, 2><<<dim3(48, 25), 256, 0, stream>>>(
        hbh, hbl, w2f, b2 + l * NEXP * DM, lists, counts, ybuf, nullptr, nullptr);
    moe_combine_ln_kernel<<<TOK, DM, 0, stream>>>(t, ybuf, gates, idxb, bias0, bias_sum,
                                                  ln2_g + l * DM, ln2_b + l * DM, tfh, tfl);
  }

  final_kernel<<<dim3(BATCH, 4), 256, 0, stream>>>(t, norm_g, norm_b, fc_w, fc_b,
                                                   (float*)d_out);
}

// Round 4
// 900.892 us; speedup vs baseline: 1.1982x; 1.0434x over previous
//
#include <hip/hip_runtime.h>
#include <hip/hip_bf16.h>

constexpr int LYR  = 4;
constexpr int DM   = 384;
constexpr int HIDN = 1536;
constexpr int NHEAD = 6;
constexpr int HDIM = 64;
constexpr int NEXP = 8;
constexpr int SEQ  = 197;
constexpr int BATCH = 8;
constexpr int TOK  = BATCH * SEQ;   // 1576
constexpr int NCLS = 1000;
constexpr int CAPE = TOK;           // max pairs per expert
constexpr int NPATCH = BATCH * 196; // 1568
constexpr float EPSLN = 1e-5f;
constexpr int KP = 40;              // LDS row pitch (bf16 elems) for patch staging

typedef __attribute__((ext_vector_type(8))) short short8v;
typedef __attribute__((ext_vector_type(4))) short short4v;
typedef __attribute__((ext_vector_type(2))) short short2v;
typedef __attribute__((ext_vector_type(4))) float f32x4v;

// ---------------- threefry2x32 (JAX-compatible) ----------------
__host__ __device__ inline void tf2x32(unsigned k0, unsigned k1, unsigned x0, unsigned x1,
                                       unsigned& y0, unsigned& y1) {
  unsigned ks2 = k0 ^ k1 ^ 0x1BD11BDAu;
  unsigned v0 = x0 + k0, v1 = x1 + k1;
#define TFR(r) { v0 += v1; v1 = (v1 << (r)) | (v1 >> (32 - (r))); v1 ^= v0; }
  TFR(13) TFR(15) TFR(26) TFR(6)
  v0 += k1;  v1 += ks2 + 1u;
  TFR(17) TFR(29) TFR(16) TFR(24)
  v0 += ks2; v1 += k0 + 2u;
  TFR(13) TFR(15) TFR(26) TFR(6)
  v0 += k0;  v1 += k1 + 3u;
  TFR(17) TFR(29) TFR(16) TFR(24)
  v0 += k1;  v1 += ks2 + 4u;
  TFR(13) TFR(15) TFR(26) TFR(6)
  v0 += ks2; v1 += k0 + 5u;
#undef TFR
  y0 = v0; y1 = v1;
}

// XLA ErfInv32 (Giles) — matches jax.lax.erf_inv for f32
__device__ inline float erfinv32(float x) {
  float w = -log1pf(-x * x);
  float p;
  if (w < 5.f) {
    w -= 2.5f;
    p = 2.81022636e-08f;
    p = fmaf(p, w, 3.43273939e-07f);
    p = fmaf(p, w, -3.5233877e-06f);
    p = fmaf(p, w, -4.39150654e-06f);
    p = fmaf(p, w, 0.00021858087f);
    p = fmaf(p, w, -0.00125372503f);
    p = fmaf(p, w, -0.00417768164f);
    p = fmaf(p, w, 0.246640727f);
    p = fmaf(p, w, 1.50140941f);
  } else {
    w = sqrtf(w) - 3.f;
    p = -0.000200214257f;
    p = fmaf(p, w, 0.000100950558f);
    p = fmaf(p, w, 0.00134934322f);
    p = fmaf(p, w, -0.00367342844f);
    p = fmaf(p, w, 0.00573950773f);
    p = fmaf(p, w, -0.0076224613f);
    p = fmaf(p, w, 0.00943887047f);
    p = fmaf(p, w, 1.00167406f);
    p = fmaf(p, w, 2.83297682f);
  }
  return p * x;
}

__device__ inline float gelu_f(float x) {
  return 0.5f * x * (1.f + erff(x * 0.70710678118654752f));
}

__device__ inline unsigned short bf16_rne(float x) {
  unsigned u = __float_as_uint(x);
  unsigned r = (u + 0x7fffu + ((u >> 16) & 1u)) >> 16;
  return (unsigned short)r;
}
__device__ inline void split2(float x, short& hs, short& ls) {
  unsigned hu = bf16_rne(x);
  float hf = __uint_as_float(hu << 16);
  unsigned lu = bf16_rne(x - hf);
  hs = (short)hu; ls = (short)lu;
}

// =====================================================================
// Weight pre-conversion: W[K][N] fp32 -> MFMA A-frag chunks, hi/lo bf16.
// =====================================================================
__global__ __launch_bounds__(256) void convw_kernel(const float* __restrict__ src,
                                                    short* __restrict__ dst,
                                                    int K, int N) {
  const int nchunks = (K >> 5) * (N >> 4);
  const int chunk = blockIdx.x * 4 + (threadIdx.x >> 6);
  if (chunk >= nchunks) return;
  const int lane = threadIdx.x & 63;
  const long eoffS = (long)blockIdx.y * K * N;
  const long eoffD = (long)blockIdx.y * nchunks * 1024;
  const int nc = N >> 4;
  const int kt = chunk / nc, nt = chunk - kt * nc;
  const int n = nt * 16 + (lane & 15);
  const int kb = kt * 32 + (lane >> 4) * 8;
  short8v hv, lv;
#pragma unroll
  for (int j = 0; j < 8; j++) {
    short h, l;
    split2(src[eoffS + (long)(kb + j) * N + n], h, l);
    hv[j] = h; lv[j] = l;
  }
  *(short8v*)&dst[eoffD + (long)chunk * 1024 + lane * 8] = hv;
  *(short8v*)&dst[eoffD + (long)chunk * 1024 + 512 + lane * 8] = lv;
}

// =====================================================================
// MFMA GEMM, LDS double-buffered, pre-split A (Ah/Al row-major [row][K]).
// One barrier per K-step; A+W prefetched into regs before the barrier.
// MODE: 0 dense fp32-out, 3 dense split-out, 1 moe1 (gelu+split-out),
// 2 moe2 fp32-out.
// =====================================================================
template <int KTOT, int NTOT, int MODE>
__global__ __launch_bounds__(256) void gemm_lds_kernel(
    const short* __restrict__ Ah, const short* __restrict__ Al,
    const short* __restrict__ Wf, const float* __restrict__ bias,
    const int* __restrict__ lists, const int* __restrict__ counts,
    float* __restrict__ outF, short* __restrict__ outH, short* __restrict__ outL) {
  constexpr bool ISMOE = (MODE == 1 || MODE == 2);
  constexpr bool SPLITOUT = (MODE == 1 || MODE == 3);
  constexpr int SPE = NTOT / 64;   // strips per expert
  constexpr int NK = KTOT / 32;
  constexpr int PIT = 36;          // LDS pitch (shorts)
  const int strip = blockIdx.x;
  int e, c0;
  if (ISMOE) { e = strip / SPE; c0 = (strip - e * SPE) * 64; }
  else { e = 0; c0 = strip * 64; if (c0 >= NTOT) return; }
  const int m = blockIdx.y;
  const int cnt = ISMOE ? counts[e] : TOK;
  if (m * 64 >= cnt) return;
  const int rowsM = min(64, cnt - m * 64);
  __shared__ int ent[64];
  __shared__ short sh[2][64 * PIT];
  __shared__ short sl[2][64 * PIT];
  const int tid = threadIdx.x;
  const int w = tid >> 6, lane = tid & 63;
  if (ISMOE) {
    if (tid < 64) ent[tid] = (tid < rowsM) ? lists[e * CAPE + m * 64 + tid] : -1;
    __syncthreads();
  }
  const int sr = tid >> 2, skq = (tid & 3) * 8;
  bool okr; long arow = 0;
  if (!ISMOE) {
    okr = (sr < rowsM);
    arow = (long)(m * 64 + (okr ? sr : 0)) * KTOT;
  } else {
    const int pid = ent[sr];
    okr = (pid >= 0);
    arow = (long)(okr ? ((MODE == 1) ? (pid >> 1) : pid) : 0) * KTOT;
  }
  const short* W = Wf + (long)e * ((KTOT >> 5) * (NTOT >> 4)) * 1024;
  const int wm = (w >> 1) * 32, wn = (w & 1) * 32;
  f32x4v Cr[2][2] = {};
  short8v ch, cl;
#pragma unroll
  for (int j = 0; j < 8; j++) { ch[j] = 0; cl[j] = 0; }
  if (okr) {
    ch = *(const short8v*)&Ah[arow + skq];
    cl = *(const short8v*)&Al[arow + skq];
  }
#pragma unroll 2
  for (int kt = 0; kt < NK; ++kt) {
    const int cb = kt & 1;
    *(short8v*)&sh[cb][sr * PIT + skq] = ch;
    *(short8v*)&sl[cb][sr * PIT + skq] = cl;
    if (kt + 1 < NK && okr) {
      ch = *(const short8v*)&Ah[arow + (kt + 1) * 32 + skq];
      cl = *(const short8v*)&Al[arow + (kt + 1) * 32 + skq];
    }
    const long wkb = ((long)kt * (NTOT >> 4) + (c0 >> 4) + (wn >> 4)) * 1024;
    short8v wh[2], wl[2];
#pragma unroll
    for (int nt = 0; nt < 2; ++nt) {
      wh[nt] = *(const short8v*)&W[wkb + nt * 1024 + lane * 8];
      wl[nt] = *(const short8v*)&W[wkb + nt * 1024 + 512 + lane * 8];
    }
    __syncthreads();
    short8v bh[2], bl[2];
#pragma unroll
    for (int tt = 0; tt < 2; ++tt) {
      const int trow = wm + tt * 16 + (lane & 15);
      bh[tt] = *(const short8v*)&sh[cb][trow * PIT + (lane >> 4) * 8];
      bl[tt] = *(const short8v*)&sl[cb][trow * PIT + (lane >> 4) * 8];
    }
#pragma unroll
    for (int nt = 0; nt < 2; ++nt) {
#pragma unroll
      for (int tt = 0; tt < 2; ++tt) {
        Cr[tt][nt] = __builtin_amdgcn_mfma_f32_16x16x32_bf16(wh[nt], bh[tt], Cr[tt][nt], 0, 0, 0);
        Cr[tt][nt] = __builtin_amdgcn_mfma_f32_16x16x32_bf16(wh[nt], bl[tt], Cr[tt][nt], 0, 0, 0);
        Cr[tt][nt] = __builtin_amdgcn_mfma_f32_16x16x32_bf16(wl[nt], bh[tt], Cr[tt][nt], 0, 0, 0);
      }
    }
  }
  const int tl = lane & 15;
  const int nq = (lane >> 4) * 4;
#pragma unroll
  for (int tt = 0; tt < 2; ++tt) {
    const int trow = wm + tt * 16 + tl;
    if (trow < rowsM) {
      const long orow = (long)(ISMOE ? ent[trow] : (m * 64 + trow)) * NTOT;
#pragma unroll
      for (int nt = 0; nt < 2; ++nt) {
        const int n = c0 + wn + nt * 16 + nq;
        const float4 bv = *(const float4*)&bias[(ISMOE ? e * NTOT : 0) + n];
        float o0 = Cr[tt][nt][0] + bv.x, o1 = Cr[tt][nt][1] + bv.y;
        float o2 = Cr[tt][nt][2] + bv.z, o3 = Cr[tt][nt][3] + bv.w;
        if (SPLITOUT) {
          if (MODE == 1) { o0 = gelu_f(o0); o1 = gelu_f(o1); o2 = gelu_f(o2); o3 = gelu_f(o3); }
          short4v hv, lv; short hs, ls;
          split2(o0, hs, ls); hv[0] = hs; lv[0] = ls;
          split2(o1, hs, ls); hv[1] = hs; lv[1] = ls;
          split2(o2, hs, ls); hv[2] = hs; lv[2] = ls;
          split2(o3, hs, ls); hv[3] = hs; lv[3] = ls;
          *(short4v*)&outH[orow + n] = hv;
          *(short4v*)&outL[orow + n] = lv;
        } else {
          *(float4*)&outF[orow + n] = make_float4(o0, o1, o2, o3);
        }
      }
    }
  }
}

// =====================================================================
// Patch embed as MFMA GEMM (gathers A from x via unfold geometry).
// =====================================================================
__global__ __launch_bounds__(256) void patch_mfma_kernel(const float* __restrict__ x,
                                                         const short* __restrict__ Wf,
                                                         const float* __restrict__ pb,
                                                         const float* __restrict__ pos,
                                                         float* __restrict__ t,
                                                         short* __restrict__ tfh,
                                                         short* __restrict__ tfl) {
  constexpr int KTOT = 768, NTOT = DM;
  const int rowsM = min(64, NPATCH - (int)blockIdx.x * 64);
  const int c0 = blockIdx.z * 64;
  const int tid = threadIdx.x;
  const int w = tid >> 6, lane = tid & 63;
  __shared__ short xh[64 * KP];
  __shared__ short xl[64 * KP];
  const int sr = tid >> 2, skq = (tid & 3) * 8;
  const bool okr = (sr < rowsM);
  const int p = blockIdx.x * 64 + sr;
  const int pbat = okr ? (p / 196) : 0;
  const int pn = okr ? (p - pbat * 196) : 0;
  const int hp = pn / 14, wp = pn - hp * 14;
  const float* xbase = x + ((long)pbat * 3 * 224 + hp * 16) * 224 + wp * 16;
  const int wm = (w >> 1) * 32, wn = (w & 1) * 32;
  f32x4v Cr[2][2] = {};
  float4 ra = make_float4(0.f, 0.f, 0.f, 0.f), rb = ra;
  if (okr) {
    const int f = skq;
    const int c = f >> 8, py = (f >> 4) & 15, px = f & 15;
    const float* ptr = xbase + ((long)c * 224 + py) * 224 + px;
    ra = *(const float4*)ptr;
    rb = *(const float4*)(ptr + 4);
  }
  for (int kt = 0; kt < KTOT / 32; ++kt) {
    __syncthreads();
    {
      const float v[8] = {ra.x, ra.y, ra.z, ra.w, rb.x, rb.y, rb.z, rb.w};
      short8v hv, lv;
#pragma unroll
      for (int j = 0; j < 8; j++) { short h, l; split2(v[j], h, l); hv[j] = h; lv[j] = l; }
      *(short8v*)&xh[sr * KP + skq] = hv;
      *(short8v*)&xl[sr * KP + skq] = lv;
    }
    if (kt + 1 < KTOT / 32 && okr) {
      const int f = (kt + 1) * 32 + skq;
      const int c = f >> 8, py = (f >> 4) & 15, px = f & 15;
      const float* ptr = xbase + ((long)c * 224 + py) * 224 + px;
      ra = *(const float4*)ptr;
      rb = *(const float4*)(ptr + 4);
    }
    __syncthreads();
    short8v bhv[2], blv[2];
#pragma unroll
    for (int tt = 0; tt < 2; ++tt) {
      const int trow = wm + tt * 16 + (lane & 15);
      bhv[tt] = *(const short8v*)&xh[trow * KP + (lane >> 4) * 8];
      blv[tt] = *(const short8v*)&xl[trow * KP + (lane >> 4) * 8];
    }
    const long wkb = ((long)kt * (NTOT >> 4) + (c0 >> 4) + (wn >> 4)) * 1024;
#pragma unroll
    for (int nt = 0; nt < 2; ++nt) {
      const short8v wh = *(const short8v*)&Wf[wkb + nt * 1024 + lane * 8];
      const short8v wl = *(const short8v*)&Wf[wkb + nt * 1024 + 512 + lane * 8];
#pragma unroll
      for (int tt = 0; tt < 2; ++tt) {
        Cr[tt][nt] = __builtin_amdgcn_mfma_f32_16x16x32_bf16(wh, bhv[tt], Cr[tt][nt], 0, 0, 0);
        Cr[tt][nt] = __builtin_amdgcn_mfma_f32_16x16x32_bf16(wh, blv[tt], Cr[tt][nt], 0, 0, 0);
        Cr[tt][nt] = __builtin_amdgcn_mfma_f32_16x16x32_bf16(wl, bhv[tt], Cr[tt][nt], 0, 0, 0);
      }
    }
  }
  const int tl = lane & 15;
  const int nq = (lane >> 4) * 4;
#pragma unroll
  for (int tt = 0; tt < 2; ++tt) {
    const int trow = wm + tt * 16 + tl;
    if (trow < rowsM) {
      const int r = blockIdx.x * 64 + trow;
      const int b2 = r / 196, n2 = r - b2 * 196;
      const long orow = (long)(b2 * SEQ + 1 + n2) * DM;
#pragma unroll
      for (int nt = 0; nt < 2; ++nt) {
        const int n = c0 + wn + nt * 16 + nq;
        const float4 bv = *(const float4*)&pb[n];
        const float4 pv = *(const float4*)&pos[(1 + n2) * DM + n];
        float o0 = Cr[tt][nt][0] + bv.x + pv.x;
        float o1 = Cr[tt][nt][1] + bv.y + pv.y;
        float o2 = Cr[tt][nt][2] + bv.z + pv.z;
        float o3 = Cr[tt][nt][3] + bv.w + pv.w;
        *(float4*)&t[orow + n] = make_float4(o0, o1, o2, o3);
        short4v hv, lv; short hs, ls;
        split2(o0, hs, ls); hv[0] = hs; lv[0] = ls;
        split2(o1, hs, ls); hv[1] = hs; lv[1] = ls;
        split2(o2, hs, ls); hv[2] = hs; lv[2] = ls;
        split2(o3, hs, ls); hv[3] = hs; lv[3] = ls;
        *(short4v*)&tfh[orow + n] = hv;
        *(short4v*)&tfl[orow + n] = lv;
      }
    }
  }
}

__global__ void cls_pos_kernel(const float* __restrict__ cls, const float* __restrict__ pos,
                               float* __restrict__ t,
                               short* __restrict__ tfh, short* __restrict__ tfl) {
  int b = blockIdx.x, d = threadIdx.x;
  float v = cls[d] + pos[d];
  t[(b * SEQ) * DM + d] = v;
  short hs, ls; split2(v, hs, ls);
  tfh[(b * SEQ) * DM + d] = hs;
  tfl[(b * SEQ) * DM + d] = ls;
}

// =====================================================================
// MFMA attention. One block per (b, h, 64-query tile); 4 waves x 16 q.
// qkv given as bf16 hi/lo split [tok][1152]. Scores via 3-mfma split,
// softmax fully in registers (row q = lane&15, keys across 4 lanes),
// P split to LDS, PV via 3-mfma with V^T staged per-32-key step.
// Output: afh/afl bf16 hi/lo split (feeds proj GEMM).
// =====================================================================
constexpr int APIT = 232;  // P row pitch (shorts): start banks spread evenly
constexpr int VPIT = 40;   // V^T row pitch (shorts)
__global__ __launch_bounds__(256) void attn_mfma_kernel(const short* __restrict__ qh,
                                                        const short* __restrict__ ql,
                                                        short* __restrict__ afh,
                                                        short* __restrict__ afl) {
  const int bh = blockIdx.x;
  const int b = bh / NHEAD, h = bh % NHEAD;
  const int q0 = blockIdx.y * 64;
  const int tid = threadIdx.x;
  const int w = tid >> 6, lane = tid & 63;
  const int tl = lane & 15, g = lane >> 4;
  __shared__ short ph[4][16 * APIT];
  __shared__ short pl[4][16 * APIT];
  __shared__ short vsh[64 * VPIT];
  __shared__ short vsl[64 * VPIT];
  const long hq = (long)h * HDIM;

  // ---- Q fragments (kept in regs) ----
  const int qrow = q0 + w * 16 + tl;
  const long qtok = (long)(b * SEQ + min(qrow, SEQ - 1)) * 1152;
  short8v qfh[2], qfl[2];
#pragma unroll
  for (int s = 0; s < 2; ++s) {
    qfh[s] = *(const short8v*)&qh[qtok + hq + s * 32 + g * 8];
    qfl[s] = *(const short8v*)&ql[qtok + hq + s * 32 + g * 8];
  }

  // ---- scores: S[q@tl][key@g*4+j] per 16-key tile ----
  f32x4v sc[13];
#pragma unroll
  for (int n = 0; n < 13; ++n) {
    f32x4v acc = {};
    const long ktok = (long)(b * SEQ + min(n * 16 + tl, SEQ - 1)) * 1152;
#pragma unroll
    for (int s = 0; s < 2; ++s) {
      const short8v kh = *(const short8v*)&qh[ktok + DM + hq + s * 32 + g * 8];
      const short8v kl = *(const short8v*)&ql[ktok + DM + hq + s * 32 + g * 8];
      acc = __builtin_amdgcn_mfma_f32_16x16x32_bf16(kh, qfh[s], acc, 0, 0, 0);
      acc = __builtin_amdgcn_mfma_f32_16x16x32_bf16(kh, qfl[s], acc, 0, 0, 0);
      acc = __builtin_amdgcn_mfma_f32_16x16x32_bf16(kl, qfh[s], acc, 0, 0, 0);
    }
    sc[n] = acc;
  }

  // ---- softmax (in-register; reduce over 4 lanes sharing tl) ----
  float m = -1e30f;
#pragma unroll
  for (int n = 0; n < 13; ++n)
#pragma unroll
    for (int j = 0; j < 4; ++j) {
      const int key = n * 16 + g * 4 + j;
      float v = sc[n][j] * 0.125f;
      v = (key < SEQ) ? v : -1e30f;
      sc[n][j] = v;
      m = fmaxf(m, v);
    }
  m = fmaxf(m, __shfl_xor(m, 16));
  m = fmaxf(m, __shfl_xor(m, 32));
  float sum = 0.f;
#pragma unroll
  for (int n = 0; n < 13; ++n)
#pragma unroll
    for (int j = 0; j < 4; ++j) {
      float p = __expf(sc[n][j] - m);
      sc[n][j] = p; sum += p;
    }
  sum += __shfl_xor(sum, 16);
  sum += __shfl_xor(sum, 32);
  const float inv = 1.f / sum;

  // ---- write P (split) to this wave's LDS region ----
  short* prowh = &ph[w][tl * APIT];
  short* prowl = &pl[w][tl * APIT];
#pragma unroll
  for (int n = 0; n < 13; ++n) {
    short4v hv, lv;
#pragma unroll
    for (int j = 0; j < 4; ++j) {
      short hs, ls; split2(sc[n][j] * inv, hs, ls);
      hv[j] = hs; lv[j] = ls;
    }
    *(short4v*)&prowh[n * 16 + g * 4] = hv;
    *(short4v*)&prowl[n * 16 + g * 4] = lv;
  }
  {  // zero-fill keys 208..223 (7th PV step reads them)
    short4v z; z[0] = 0; z[1] = 0; z[2] = 0; z[3] = 0;
    *(short4v*)&prowh[208 + g * 4] = z;
    *(short4v*)&prowl[208 + g * 4] = z;
  }

  // ---- PV: 7 steps of 32 keys; V^T staged [d][key] in LDS ----
  // staging map: 2 keys x 4 d per thread, short2 writes (2-way max)
  const int kp = (tid & 15) * 2;        // key pair base
  const int dg = (tid >> 4) * 4;        // 4 d's
  f32x4v oacc[4] = {};
  short4v r0h, r0l, r1h, r1l;
  {
    const long t0 = (long)(b * SEQ + min(kp, SEQ - 1)) * 1152 + 2 * DM + hq + dg;
    const long t1 = (long)(b * SEQ + min(kp + 1, SEQ - 1)) * 1152 + 2 * DM + hq + dg;
    r0h = *(const short4v*)&qh[t0]; r0l = *(const short4v*)&ql[t0];
    r1h = *(const short4v*)&qh[t1]; r1l = *(const short4v*)&ql[t1];
  }
  for (int st = 0; st < 7; ++st) {
    __syncthreads();  // previous step's reads done
#pragma unroll
    for (int jj = 0; jj < 4; ++jj) {
      short2v h2; h2[0] = r0h[jj]; h2[1] = r1h[jj];
      short2v l2; l2[0] = r0l[jj]; l2[1] = r1l[jj];
      *(short2v*)&vsh[(dg + jj) * VPIT + kp] = h2;
      *(short2v*)&vsl[(dg + jj) * VPIT + kp] = l2;
    }
    if (st + 1 < 7) {
      const int kb = (st + 1) * 32;
      const long t0 = (long)(b * SEQ + min(kb + kp, SEQ - 1)) * 1152 + 2 * DM + hq + dg;
      const long t1 = (long)(b * SEQ + min(kb + kp + 1, SEQ - 1)) * 1152 + 2 * DM + hq + dg;
      r0h = *(const short4v*)&qh[t0]; r0l = *(const short4v*)&ql[t0];
      r1h = *(const short4v*)&qh[t1]; r1l = *(const short4v*)&ql[t1];
    }
    __syncthreads();  // V^T visible
    const short8v pbh = *(const short8v*)&prowh[st * 32 + g * 8];
    const short8v pbl = *(const short8v*)&prowl[st * 32 + g * 8];
#pragma unroll
    for (int dt = 0; dt < 4; ++dt) {
      const short8v vfh = *(const short8v*)&vsh[(dt * 16 + tl) * VPIT + g * 8];
      const short8v vfl = *(const short8v*)&vsl[(dt * 16 + tl) * VPIT + g * 8];
      oacc[dt] = __builtin_amdgcn_mfma_f32_16x16x32_bf16(vfh, pbh, oacc[dt], 0, 0, 0);
      oacc[dt] = __builtin_amdgcn_mfma_f32_16x16x32_bf16(vfh, pbl, oacc[dt], 0, 0, 0);
      oacc[dt] = __builtin_amdgcn_mfma_f32_16x16x32_bf16(vfl, pbh, oacc[dt], 0, 0, 0);
    }
  }

  // ---- epilogue: O[q@tl][d@dt*16+g*4+j] -> split afh/afl ----
  if (qrow < SEQ) {
    const long obase = (long)(b * SEQ + qrow) * DM + hq;
#pragma unroll
    for (int dt = 0; dt < 4; ++dt) {
      short4v hv, lv; short hs, ls;
      split2(oacc[dt][0], hs, ls); hv[0] = hs; lv[0] = ls;
      split2(oacc[dt][1], hs, ls); hv[1] = hs; lv[1] = ls;
      split2(oacc[dt][2], hs, ls); hv[2] = hs; lv[2] = ls;
      split2(oacc[dt][3], hs, ls); hv[3] = hs; lv[3] = ls;
      *(short4v*)&afh[obase + dt * 16 + g * 4] = hv;
      *(short4v*)&afl[obase + dt * 16 + g * 4] = lv;
    }
  }
}

// ---------------- residual add + LayerNorm (per token) ----------------
__global__ __launch_bounds__(384) void add_ln_kernel(float* __restrict__ t,
                                                     const float* __restrict__ delta,
                                                     const float* __restrict__ g,
                                                     const float* __restrict__ bta,
                                                     short* __restrict__ tfh,
                                                     short* __restrict__ tfl) {
  int tok = blockIdx.x, d = threadIdx.x;
  float v = t[tok * DM + d] + delta[tok * DM + d];
  float sv = v, sq = v * v;
  for (int off = 32; off > 0; off >>= 1) { sv += __shfl_xor(sv, off); sq += __shfl_xor(sq, off); }
  __shared__ float rs[6], rq[6];
  int w = d >> 6, ln = d & 63;
  if (ln == 0) { rs[w] = sv; rq[w] = sq; }
  __syncthreads();
  float mean = 0.f, ms = 0.f;
#pragma unroll
  for (int i = 0; i < 6; i++) { mean += rs[i]; ms += rq[i]; }
  mean *= (1.f / DM); ms *= (1.f / DM);
  float inv = rsqrtf(ms - mean * mean + EPSLN);
  float y = (v - mean) * inv * g[d] + bta[d];
  t[tok * DM + d] = y;
  short hs, ls; split2(y, hs, ls);
  tfh[tok * DM + d] = hs;
  tfl[tok * DM + d] = ls;
}

// ---------------- router logits + top-2 (no global atomics) ----------------
__global__ __launch_bounds__(256) void router_logits_kernel(const float* __restrict__ t,
                                                            const float* __restrict__ rw,
                                                            const float* __restrict__ rb,
                                                            unsigned k0, unsigned k1,
                                                            float* __restrict__ gates,
                                                            int* __restrict__ idxb) {
  const int tok = blockIdx.x * 4 + (threadIdx.x >> 6);
  const int lane = threadIdx.x & 63;
  const int e = lane & 7, j = lane >> 3;
  const float* xr = t + tok * DM;
  float acc = 0.f;
  for (int d2 = j * 48; d2 < j * 48 + 48; d2++) acc += xr[d2] * rw[d2 * NEXP + e];
  acc += __shfl_xor(acc, 8);
  acc += __shfl_xor(acc, 16);
  acc += __shfl_xor(acc, 32);
  if (lane < 8) {
    acc += rb[e];
    unsigned i = (unsigned)(tok * NEXP + e);
    unsigned y0, y1;
    tf2x32(k0, k1, 0u, i, y0, y1);
    unsigned bits = y0 ^ y1;
    float f = __uint_as_float(0x3f800000u | (bits >> 9)) - 1.0f;
    const float lo = -0.99999994f;
    float u = f * 2.0f + lo;
    u = fmaxf(lo, u);
    acc += 0.01f * (1.41421356f * erfinv32(u));
  }
  float lg[8];
#pragma unroll
  for (int qq = 0; qq < 8; qq++) lg[qq] = __shfl(acc, qq);
  if (lane == 0) {
    int i0 = 0; float v0 = lg[0];
#pragma unroll
    for (int qq = 1; qq < 8; qq++) if (lg[qq] > v0) { v0 = lg[qq]; i0 = qq; }
    int i1 = -1; float v1 = -1e30f;
#pragma unroll
    for (int qq = 0; qq < 8; qq++) if (qq != i0 && lg[qq] > v1) { v1 = lg[qq]; i1 = qq; }
    float e1 = __expf(v1 - v0);
    float g0 = 1.f / (1.f + e1);
    idxb[tok * 2] = i0; idxb[tok * 2 + 1] = i1;
    gates[tok * 2] = g0; gates[tok * 2 + 1] = 1.f - g0;
  }
}

// ---------------- bucket: single block bins all pairs via LDS atomics ----------------
__global__ __launch_bounds__(1024) void bucket_kernel(const int* __restrict__ idxb,
                                                      int* __restrict__ lists,
                                                      int* __restrict__ counts,
                                                      int* __restrict__ occ) {
  __shared__ int lc[NEXP];
  __shared__ int locc[2 * NEXP];
  const int tid = threadIdx.x;
  if (tid < NEXP) lc[tid] = 0;
  if (tid < 2 * NEXP) locc[tid] = 0;
  __syncthreads();
  for (int i = tid; i < 2 * TOK; i += 1024) {
    const int e = idxb[i];
    const int p = atomicAdd(&lc[e], 1);
    lists[e * CAPE + p] = i;
    locc[(i & 1) * NEXP + e] = 1;
  }
  __syncthreads();
  if (tid < NEXP) counts[tid] = lc[tid];
  if (tid < 2 * NEXP) occ[tid] = locc[tid];
}

// ---------------- prep: bias0 = b2 ----------------
__global__ void prep_kernel(const float* __restrict__ b2, float* __restrict__ bias0) {
  int e = blockIdx.x, c = threadIdx.x;
  bias0[e * DM + c] = b2[e * DM + c];
}

// ---------------- bias0 += gelu(b1)@W2 partial over K-chunks ----------------
__global__ __launch_bounds__(384) void bias0_partial_kernel(const float* __restrict__ b1,
                                                            const float* __restrict__ w2,
                                                            float* __restrict__ bias0) {
  const int e = blockIdx.x, kc = blockIdx.y;
  __shared__ float gb[128];
  const int tid = threadIdx.x;
  if (tid < 128) gb[tid] = gelu_f(b1[e * HIDN + kc * 128 + tid]);
  __syncthreads();
  float acc = 0.f;
  const float* W = w2 + ((long)e * HIDN + kc * 128) * DM + tid;
  for (int j2 = 0; j2 < 128; j2++) acc += gb[j2] * W[(long)j2 * DM];
  atomicAdd(&bias0[e * DM + tid], acc);
}

__global__ __launch_bounds__(384) void bias_sum_kernel(const float* __restrict__ bias0,
                                                       const int* __restrict__ occ,
                                                       float* __restrict__ bias_sum) {
  int k = blockIdx.x, d = threadIdx.x;
  float acc = 0.f;
#pragma unroll
  for (int e = 0; e < NEXP; e++)
    if (occ[k * NEXP + e]) acc += bias0[e * DM + d];
  bias_sum[k * DM + d] = acc;
}

// ---------------- combine experts + residual + LN2 ----------------
__global__ __launch_bounds__(384) void moe_combine_ln_kernel(float* __restrict__ t,
                                                             const float* __restrict__ ybuf,
                                                             const float* __restrict__ gates,
                                                             const int* __restrict__ idxb,
                                                             const float* __restrict__ bias0,
                                                             const float* __restrict__ bias_sum,
                                                             const float* __restrict__ g,
                                                             const float* __restrict__ bta,
                                                             short* __restrict__ tfh,
                                                             short* __restrict__ tfl) {
  int tok = blockIdx.x, d = threadIdx.x;
  float g0 = gates[tok * 2], g1 = gates[tok * 2 + 1];
  int i0 = idxb[tok * 2], i1 = idxb[tok * 2 + 1];
  float m0 = ybuf[(tok * 2) * DM + d] - bias0[i0 * DM + d] + bias_sum[d];
  float m1 = ybuf[(tok * 2 + 1) * DM + d] - bias0[i1 * DM + d] + bias_sum[DM + d];
  float v = t[tok * DM + d] + g0 * m0 + g1 * m1;
  float sv = v, sq = v * v;
  for (int off = 32; off > 0; off >>= 1) { sv += __shfl_xor(sv, off); sq += __shfl_xor(sq, off); }
  __shared__ float rs[6], rq[6];
  int w = d >> 6, ln = d & 63;
  if (ln == 0) { rs[w] = sv; rq[w] = sq; }
  __syncthreads();
  float mean = 0.f, ms = 0.f;
#pragma unroll
  for (int i = 0; i < 6; i++) { mean += rs[i]; ms += rq[i]; }
  mean *= (1.f / DM); ms *= (1.f / DM);
  float inv = rsqrtf(ms - mean * mean + EPSLN);
  float y = (v - mean) * inv * g[d] + bta[d];
  t[tok * DM + d] = y;
  short hs, ls; split2(y, hs, ls);
  tfh[tok * DM + d] = hs;
  tfl[tok * DM + d] = ls;
}

// ---------------- final: LN(cls) @ fc_w + fc_b ----------------
__global__ __launch_bounds__(256) void final_kernel(const float* __restrict__ t,
                                                    const float* __restrict__ ng,
                                                    const float* __restrict__ nb,
                                                    const float* __restrict__ fw,
                                                    const float* __restrict__ fb,
                                                    float* __restrict__ out) {
  int b = blockIdx.x, chunk = blockIdx.y, tid = threadIdx.x;
  __shared__ float xr[DM];
  __shared__ float rs[4], rq[4];
  const float* row = t + (b * SEQ) * DM;
  float sv = 0.f, sq = 0.f;
  for (int i = tid; i < DM; i += 256) { float x = row[i]; xr[i] = x; sv += x; sq += x * x; }
  for (int off = 32; off > 0; off >>= 1) { sv += __shfl_xor(sv, off); sq += __shfl_xor(sq, off); }
  int w = tid >> 6, ln = tid & 63;
  if (ln == 0) { rs[w] = sv; rq[w] = sq; }
  __syncthreads();
  float mean = (rs[0] + rs[1] + rs[2] + rs[3]) * (1.f / DM);
  float ms = (rq[0] + rq[1] + rq[2] + rq[3]) * (1.f / DM);
  float inv = rsqrtf(ms - mean * mean + EPSLN);
  for (int i = tid; i < DM; i += 256) xr[i] = (xr[i] - mean) * inv * ng[i] + nb[i];
  __syncthreads();
  int c = chunk * 250 + tid;
  if (tid < 250) {
    float acc = fb[c];
    for (int k = 0; k < DM; k++) acc += xr[k] * fw[k * NCLS + c];
    out[b * NCLS + c] = acc;
  }
}

extern "C" void kernel_launch(void* const* d_in, const int* in_sizes, int n_in,
                              void* d_out, int out_size, void* d_ws, size_t ws_size,
                              hipStream_t stream) {
  const float* x       = (const float*)d_in[0];
  const float* patch_w = (const float*)d_in[1];
  const float* patch_b = (const float*)d_in[2];
  const float* cls_tok = (const float*)d_in[3];
  const float* pos     = (const float*)d_in[4];
  const float* qkv_w   = (const float*)d_in[5];
  const float* qkv_b   = (const float*)d_in[6];
  const float* proj_w  = (const float*)d_in[7];
  const float* proj_b  = (const float*)d_in[8];
  const float* ln1_g   = (const float*)d_in[9];
  const float* ln1_b   = (const float*)d_in[10];
  const float* ln2_g   = (const float*)d_in[11];
  const float* ln2_b   = (const float*)d_in[12];
  const float* router_w = (const float*)d_in[13];
  const float* router_b = (const float*)d_in[14];
  const float* w1      = (const float*)d_in[15];
  const float* b1      = (const float*)d_in[16];
  const float* w2      = (const float*)d_in[17];
  const float* b2      = (const float*)d_in[18];
  const float* norm_g  = (const float*)d_in[19];
  const float* norm_b  = (const float*)d_in[20];
  const float* fc_w    = (const float*)d_in[21];
  const float* fc_b    = (const float*)d_in[22];

  float* ws = (float*)d_ws;
  float* t        = ws;                      // TOK*DM
  float* proj     = t + TOK * DM;            // TOK*DM
  float* ybuf     = proj + TOK * DM;         // TOK*2*DM
  float* bias0    = ybuf + TOK * 2 * DM;     // NEXP*DM
  float* bias_sum = bias0 + NEXP * DM;       // 2*DM
  float* gates    = bias_sum + 2 * DM;       // TOK*2
  int* idxb   = (int*)(gates + TOK * 2);     // TOK*2
  int* lists  = idxb + TOK * 2;              // NEXP*CAPE
  int* counts = lists + NEXP * CAPE;         // NEXP
  int* occ    = counts + NEXP;               // 2*NEXP
  short* tfh = (short*)(occ + 2 * NEXP);     // TOK*DM (16B-aligned)
  short* tfl = tfh + TOK * DM;
  short* afh = tfl + TOK * DM;
  short* afl = afh + TOK * DM;
  short* qvh = afl + TOK * DM;               // TOK*1152
  short* qvl = qvh + TOK * 1152;             // TOK*1152
  short* hbh = qvl + TOK * 1152;             // 2*TOK*HIDN
  short* hbl = hbh + 2 * TOK * HIDN;         // 2*TOK*HIDN
  short* wqf = hbl + 2 * TOK * HIDN;         // 864*1024
  short* wpf = wqf + 864 * 1024;             // 288*1024
  short* w1f = wpf + 288 * 1024;             // 8*1152*1024
  short* w2f = w1f + 8 * 1152 * 1024;        // 8*1152*1024
  short* wpatf = w2f + 8 * 1152 * 1024;      // 576*1024

  convw_kernel<<<dim3(144, 1), 256, 0, stream>>>(patch_w, wpatf, 768, DM);
  patch_mfma_kernel<<<dim3(25, 1, 6), 256, 0, stream>>>(x, wpatf, patch_b, pos, t, tfh, tfl);
  cls_pos_kernel<<<BATCH, DM, 0, stream>>>(cls_tok, pos, t, tfh, tfl);

  for (int l = 0; l < LYR; l++) {
    convw_kernel<<<dim3(216, 1), 256, 0, stream>>>(qkv_w + (long)l * DM * 1152, wqf, DM, 1152);
    convw_kernel<<<dim3(72, 1), 256, 0, stream>>>(proj_w + (long)l * DM * DM, wpf, DM, DM);
    convw_kernel<<<dim3(288, NEXP), 256, 0, stream>>>(w1 + (long)l * NEXP * DM * HIDN, w1f, DM, HIDN);
    convw_kernel<<<dim3(288, NEXP), 256, 0, stream>>>(w2 + (long)l * NEXP * HIDN * DM, w2f, HIDN, DM);

    gemm_lds_kernel<DM, 1152, 3><<<dim3(24, 25), 256, 0, stream>>>(
        tfh, tfl, wqf, qkv_b + l * 1152, nullptr, nullptr, nullptr, qvh, qvl);
    attn_mfma_kernel<<<dim3(BATCH * NHEAD, 4), 256, 0, stream>>>(qvh, qvl, afh, afl);
    gemm_lds_kernel<DM, DM, 0><<<dim3(8, 25), 256, 0, stream>>>(
        afh, afl, wpf, proj_b + l * DM, nullptr, nullptr, proj, nullptr, nullptr);
    add_ln_kernel<<<TOK, DM, 0, stream>>>(t, proj, ln1_g + l * DM, ln1_b + l * DM, tfh, tfl);

    prep_kernel<<<NEXP, DM, 0, stream>>>(b2 + l * NEXP * DM, bias0);
    bias0_partial_kernel<<<dim3(NEXP, 12), 384, 0, stream>>>(
        b1 + l * NEXP * HIDN, w2 + (long)l * NEXP * HIDN * DM, bias0);
    unsigned kl0, kl1;
    tf2x32(0u, 42u, 0u, (unsigned)l, kl0, kl1);
    router_logits_kernel<<<TOK / 4, 256, 0, stream>>>(
        t, router_w + l * DM * NEXP, router_b + l * NEXP, kl0, kl1, gates, idxb);
    bucket_kernel<<<1, 1024, 0, stream>>>(idxb, lists, counts, occ);
    bias_sum_kernel<<<2, 384, 0, stream>>>(bias0, occ, bias_sum);
    gemm_lds_kernel<DM, HIDN, 1><<<dim3(192, 25), 256, 0, stream>>>(
        tfh, tfl, w1f, b1 + l * NEXP * HIDN, lists, counts, nullptr, hbh, hbl);
    gemm_lds_kernel<HIDN, DM, 2><<<dim3(48, 25), 256, 0, stream>>>(
        hbh, hbl, w2f, b2 + l * NEXP * DM, lists, counts, ybuf, nullptr, nullptr);
    moe_combine_ln_kernel<<<TOK, DM, 0, stream>>>(t, ybuf, gates, idxb, bias0, bias_sum,
                                                  ln2_g + l * DM, ln2_b + l * DM, tfh, tfl);
  }

  final_kernel<<<dim3(BATCH, 4), 256, 0, stream>>>(t, norm_g, norm_b, fc_w, fc_b,
                                                   (float*)d_out);
}

// Round 5
// 824.300 us; speedup vs baseline: 1.3095x; 1.0929x over previous
//
#include <hip/hip_runtime.h>
#include <hip/hip_bf16.h>

constexpr int LYR  = 4;
constexpr int DM   = 384;
constexpr int HIDN = 1536;
constexpr int NHEAD = 6;
constexpr int HDIM = 64;
constexpr int NEXP = 8;
constexpr int SEQ  = 197;
constexpr int BATCH = 8;
constexpr int TOK  = BATCH * SEQ;   // 1576
constexpr int NCLS = 1000;
constexpr int CAPE = TOK;           // max pairs per expert
constexpr int NPATCH = BATCH * 196; // 1568
constexpr float EPSLN = 1e-5f;
constexpr int KP = 40;              // LDS row pitch (bf16 elems) for patch staging

typedef __attribute__((ext_vector_type(8))) short short8v;
typedef __attribute__((ext_vector_type(4))) short short4v;
typedef __attribute__((ext_vector_type(2))) short short2v;
typedef __attribute__((ext_vector_type(4))) float f32x4v;

// ---------------- threefry2x32 (JAX-compatible) ----------------
__host__ __device__ inline void tf2x32(unsigned k0, unsigned k1, unsigned x0, unsigned x1,
                                       unsigned& y0, unsigned& y1) {
  unsigned ks2 = k0 ^ k1 ^ 0x1BD11BDAu;
  unsigned v0 = x0 + k0, v1 = x1 + k1;
#define TFR(r) { v0 += v1; v1 = (v1 << (r)) | (v1 >> (32 - (r))); v1 ^= v0; }
  TFR(13) TFR(15) TFR(26) TFR(6)
  v0 += k1;  v1 += ks2 + 1u;
  TFR(17) TFR(29) TFR(16) TFR(24)
  v0 += ks2; v1 += k0 + 2u;
  TFR(13) TFR(15) TFR(26) TFR(6)
  v0 += k0;  v1 += k1 + 3u;
  TFR(17) TFR(29) TFR(16) TFR(24)
  v0 += k1;  v1 += ks2 + 4u;
  TFR(13) TFR(15) TFR(26) TFR(6)
  v0 += ks2; v1 += k0 + 5u;
#undef TFR
  y0 = v0; y1 = v1;
}

// XLA ErfInv32 (Giles) — matches jax.lax.erf_inv for f32
__device__ inline float erfinv32(float x) {
  float w = -log1pf(-x * x);
  float p;
  if (w < 5.f) {
    w -= 2.5f;
    p = 2.81022636e-08f;
    p = fmaf(p, w, 3.43273939e-07f);
    p = fmaf(p, w, -3.5233877e-06f);
    p = fmaf(p, w, -4.39150654e-06f);
    p = fmaf(p, w, 0.00021858087f);
    p = fmaf(p, w, -0.00125372503f);
    p = fmaf(p, w, -0.00417768164f);
    p = fmaf(p, w, 0.246640727f);
    p = fmaf(p, w, 1.50140941f);
  } else {
    w = sqrtf(w) - 3.f;
    p = -0.000200214257f;
    p = fmaf(p, w, 0.000100950558f);
    p = fmaf(p, w, 0.00134934322f);
    p = fmaf(p, w, -0.00367342844f);
    p = fmaf(p, w, 0.00573950773f);
    p = fmaf(p, w, -0.0076224613f);
    p = fmaf(p, w, 0.00943887047f);
    p = fmaf(p, w, 1.00167406f);
    p = fmaf(p, w, 2.83297682f);
  }
  return p * x;
}

__device__ inline float gelu_f(float x) {
  return 0.5f * x * (1.f + erff(x * 0.70710678118654752f));
}

__device__ inline unsigned short bf16_rne(float x) {
  unsigned u = __float_as_uint(x);
  unsigned r = (u + 0x7fffu + ((u >> 16) & 1u)) >> 16;
  return (unsigned short)r;
}
__device__ inline void split2(float x, short& hs, short& ls) {
  unsigned hu = bf16_rne(x);
  float hf = __uint_as_float(hu << 16);
  unsigned lu = bf16_rne(x - hf);
  hs = (short)hu; ls = (short)lu;
}

// =====================================================================
// Weight pre-conversion: W[K][N] fp32 -> MFMA A-frag chunks, hi/lo bf16.
// Batched over layers via blockIdx.z with element strides.
// =====================================================================
__global__ __launch_bounds__(256) void convw_kernel(const float* __restrict__ src,
                                                    short* __restrict__ dst,
                                                    int K, int N,
                                                    long srcLS, long dstLS) {
  const int nchunks = (K >> 5) * (N >> 4);
  const int chunk = blockIdx.x * 4 + (threadIdx.x >> 6);
  if (chunk >= nchunks) return;
  const int lane = threadIdx.x & 63;
  const long loS = (long)blockIdx.z * srcLS;
  const long loD = (long)blockIdx.z * dstLS;
  const long eoffS = loS + (long)blockIdx.y * K * N;
  const long eoffD = loD + (long)blockIdx.y * nchunks * 1024;
  const int nc = N >> 4;
  const int kt = chunk / nc, nt = chunk - kt * nc;
  const int n = nt * 16 + (lane & 15);
  const int kb = kt * 32 + (lane >> 4) * 8;
  short8v hv, lv;
#pragma unroll
  for (int j = 0; j < 8; j++) {
    short h, l;
    split2(src[eoffS + (long)(kb + j) * N + n], h, l);
    hv[j] = h; lv[j] = l;
  }
  *(short8v*)&dst[eoffD + (long)chunk * 1024 + lane * 8] = hv;
  *(short8v*)&dst[eoffD + (long)chunk * 1024 + 512 + lane * 8] = lv;
}

// =====================================================================
// MFMA GEMM, BK=64 double-buffered LDS, pre-split A ([row][K] hi/lo).
// One barrier per 64-wide K step; 24 MFMAs per step per wave.
// MODE: 0 dense fp32-out, 3 dense split-out, 1 moe1 (gelu+split-out),
// 2 moe2 fp32-out. Grid (strips, m); strip fast-dim (strips%8==0) so all
// M-blocks of a W-strip share an XCD.
// =====================================================================
template <int KTOT, int NTOT, int MODE>
__global__ __launch_bounds__(256) void gemm_lds_kernel(
    const short* __restrict__ Ah, const short* __restrict__ Al,
    const short* __restrict__ Wf, const float* __restrict__ bias,
    const int* __restrict__ lists, const int* __restrict__ counts,
    float* __restrict__ outF, short* __restrict__ outH, short* __restrict__ outL) {
  constexpr bool ISMOE = (MODE == 1 || MODE == 2);
  constexpr bool SPLITOUT = (MODE == 1 || MODE == 3);
  constexpr int SPE = NTOT / 64;   // strips per expert
  constexpr int NK = KTOT / 64;    // 64-wide K steps
  constexpr int PIT = 72;          // shorts/row: 144B (16B-aligned, 2-way banks)
  const int strip = blockIdx.x;
  int e, c0;
  if (ISMOE) { e = strip / SPE; c0 = (strip - e * SPE) * 64; }
  else { e = 0; c0 = strip * 64; if (c0 >= NTOT) return; }
  const int m = blockIdx.y;
  const int cnt = ISMOE ? counts[e] : TOK;
  if (m * 64 >= cnt) return;
  const int rowsM = min(64, cnt - m * 64);
  __shared__ int ent[64];
  __shared__ short sh[2][64 * PIT];
  __shared__ short sl[2][64 * PIT];
  const int tid = threadIdx.x;
  const int w = tid >> 6, lane = tid & 63;
  if (ISMOE) {
    if (tid < 64) ent[tid] = (tid < rowsM) ? lists[e * CAPE + m * 64 + tid] : -1;
    __syncthreads();
  }
  const int sr = tid >> 2, skq = (tid & 3) * 8;
  bool okr; long arow = 0;
  if (!ISMOE) {
    okr = (sr < rowsM);
    arow = (long)(m * 64 + (okr ? sr : 0)) * KTOT;
  } else {
    const int pid = ent[sr];
    okr = (pid >= 0);
    arow = (long)(okr ? ((MODE == 1) ? (pid >> 1) : pid) : 0) * KTOT;
  }
  const short* W = Wf + (long)e * ((KTOT >> 5) * (NTOT >> 4)) * 1024;
  const int wm = (w >> 1) * 32, wn = (w & 1) * 32;
  f32x4v Cr[2][2] = {};
  short8v c0h, c1h, c0l, c1l;
#pragma unroll
  for (int j = 0; j < 8; j++) { c0h[j] = 0; c1h[j] = 0; c0l[j] = 0; c1l[j] = 0; }
  if (okr) {
    c0h = *(const short8v*)&Ah[arow + skq];
    c1h = *(const short8v*)&Ah[arow + 32 + skq];
    c0l = *(const short8v*)&Al[arow + skq];
    c1l = *(const short8v*)&Al[arow + 32 + skq];
  }
  for (int kt = 0; kt < NK; ++kt) {
    const int cb = kt & 1;
    *(short8v*)&sh[cb][sr * PIT + skq] = c0h;
    *(short8v*)&sh[cb][sr * PIT + 32 + skq] = c1h;
    *(short8v*)&sl[cb][sr * PIT + skq] = c0l;
    *(short8v*)&sl[cb][sr * PIT + 32 + skq] = c1l;
    if (kt + 1 < NK && okr) {
      const long ab = arow + (kt + 1) * 64;
      c0h = *(const short8v*)&Ah[ab + skq];
      c1h = *(const short8v*)&Ah[ab + 32 + skq];
      c0l = *(const short8v*)&Al[ab + skq];
      c1l = *(const short8v*)&Al[ab + 32 + skq];
    }
    short8v wh[2][2], wl[2][2];
#pragma unroll
    for (int kk = 0; kk < 2; ++kk) {
      const long wkb = ((long)(kt * 2 + kk) * (NTOT >> 4) + (c0 >> 4) + (wn >> 4)) * 1024;
#pragma unroll
      for (int nt = 0; nt < 2; ++nt) {
        wh[kk][nt] = *(const short8v*)&W[wkb + nt * 1024 + lane * 8];
        wl[kk][nt] = *(const short8v*)&W[wkb + nt * 1024 + 512 + lane * 8];
      }
    }
    __syncthreads();
#pragma unroll
    for (int kk = 0; kk < 2; ++kk) {
      short8v bh[2], bl[2];
#pragma unroll
      for (int tt = 0; tt < 2; ++tt) {
        const int trow = wm + tt * 16 + (lane & 15);
        bh[tt] = *(const short8v*)&sh[cb][trow * PIT + kk * 32 + (lane >> 4) * 8];
        bl[tt] = *(const short8v*)&sl[cb][trow * PIT + kk * 32 + (lane >> 4) * 8];
      }
#pragma unroll
      for (int nt = 0; nt < 2; ++nt) {
#pragma unroll
        for (int tt = 0; tt < 2; ++tt) {
          Cr[tt][nt] = __builtin_amdgcn_mfma_f32_16x16x32_bf16(wh[kk][nt], bh[tt], Cr[tt][nt], 0, 0, 0);
          Cr[tt][nt] = __builtin_amdgcn_mfma_f32_16x16x32_bf16(wh[kk][nt], bl[tt], Cr[tt][nt], 0, 0, 0);
          Cr[tt][nt] = __builtin_amdgcn_mfma_f32_16x16x32_bf16(wl[kk][nt], bh[tt], Cr[tt][nt], 0, 0, 0);
        }
      }
    }
  }
  const int tl = lane & 15;
  const int nq = (lane >> 4) * 4;
#pragma unroll
  for (int tt = 0; tt < 2; ++tt) {
    const int trow = wm + tt * 16 + tl;
    if (trow < rowsM) {
      const long orow = (long)(ISMOE ? ent[trow] : (m * 64 + trow)) * NTOT;
#pragma unroll
      for (int nt = 0; nt < 2; ++nt) {
        const int n = c0 + wn + nt * 16 + nq;
        const float4 bv = *(const float4*)&bias[(ISMOE ? e * NTOT : 0) + n];
        float o0 = Cr[tt][nt][0] + bv.x, o1 = Cr[tt][nt][1] + bv.y;
        float o2 = Cr[tt][nt][2] + bv.z, o3 = Cr[tt][nt][3] + bv.w;
        if (SPLITOUT) {
          if (MODE == 1) { o0 = gelu_f(o0); o1 = gelu_f(o1); o2 = gelu_f(o2); o3 = gelu_f(o3); }
          short4v hv, lv; short hs, ls;
          split2(o0, hs, ls); hv[0] = hs; lv[0] = ls;
          split2(o1, hs, ls); hv[1] = hs; lv[1] = ls;
          split2(o2, hs, ls); hv[2] = hs; lv[2] = ls;
          split2(o3, hs, ls); hv[3] = hs; lv[3] = ls;
          *(short4v*)&outH[orow + n] = hv;
          *(short4v*)&outL[orow + n] = lv;
        } else {
          *(float4*)&outF[orow + n] = make_float4(o0, o1, o2, o3);
        }
      }
    }
  }
}

// =====================================================================
// Patch embed as MFMA GEMM (gathers A from x via unfold geometry).
// =====================================================================
__global__ __launch_bounds__(256) void patch_mfma_kernel(const float* __restrict__ x,
                                                         const short* __restrict__ Wf,
                                                         const float* __restrict__ pb,
                                                         const float* __restrict__ pos,
                                                         float* __restrict__ t,
                                                         short* __restrict__ tfh,
                                                         short* __restrict__ tfl) {
  constexpr int KTOT = 768, NTOT = DM;
  const int rowsM = min(64, NPATCH - (int)blockIdx.x * 64);
  const int c0 = blockIdx.z * 64;
  const int tid = threadIdx.x;
  const int w = tid >> 6, lane = tid & 63;
  __shared__ short xh[64 * KP];
  __shared__ short xl[64 * KP];
  const int sr = tid >> 2, skq = (tid & 3) * 8;
  const bool okr = (sr < rowsM);
  const int p = blockIdx.x * 64 + sr;
  const int pbat = okr ? (p / 196) : 0;
  const int pn = okr ? (p - pbat * 196) : 0;
  const int hp = pn / 14, wp = pn - hp * 14;
  const float* xbase = x + ((long)pbat * 3 * 224 + hp * 16) * 224 + wp * 16;
  const int wm = (w >> 1) * 32, wn = (w & 1) * 32;
  f32x4v Cr[2][2] = {};
  float4 ra = make_float4(0.f, 0.f, 0.f, 0.f), rb = ra;
  if (okr) {
    const int f = skq;
    const int c = f >> 8, py = (f >> 4) & 15, px = f & 15;
    const float* ptr = xbase + ((long)c * 224 + py) * 224 + px;
    ra = *(const float4*)ptr;
    rb = *(const float4*)(ptr + 4);
  }
  for (int kt = 0; kt < KTOT / 32; ++kt) {
    __syncthreads();
    {
      const float v[8] = {ra.x, ra.y, ra.z, ra.w, rb.x, rb.y, rb.z, rb.w};
      short8v hv, lv;
#pragma unroll
      for (int j = 0; j < 8; j++) { short h, l; split2(v[j], h, l); hv[j] = h; lv[j] = l; }
      *(short8v*)&xh[sr * KP + skq] = hv;
      *(short8v*)&xl[sr * KP + skq] = lv;
    }
    if (kt + 1 < KTOT / 32 && okr) {
      const int f = (kt + 1) * 32 + skq;
      const int c = f >> 8, py = (f >> 4) & 15, px = f & 15;
      const float* ptr = xbase + ((long)c * 224 + py) * 224 + px;
      ra = *(const float4*)ptr;
      rb = *(const float4*)(ptr + 4);
    }
    __syncthreads();
    short8v bhv[2], blv[2];
#pragma unroll
    for (int tt = 0; tt < 2; ++tt) {
      const int trow = wm + tt * 16 + (lane & 15);
      bhv[tt] = *(const short8v*)&xh[trow * KP + (lane >> 4) * 8];
      blv[tt] = *(const short8v*)&xl[trow * KP + (lane >> 4) * 8];
    }
    const long wkb = ((long)kt * (NTOT >> 4) + (c0 >> 4) + (wn >> 4)) * 1024;
#pragma unroll
    for (int nt = 0; nt < 2; ++nt) {
      const short8v wh = *(const short8v*)&Wf[wkb + nt * 1024 + lane * 8];
      const short8v wl = *(const short8v*)&Wf[wkb + nt * 1024 + 512 + lane * 8];
#pragma unroll
      for (int tt = 0; tt < 2; ++tt) {
        Cr[tt][nt] = __builtin_amdgcn_mfma_f32_16x16x32_bf16(wh, bhv[tt], Cr[tt][nt], 0, 0, 0);
        Cr[tt][nt] = __builtin_amdgcn_mfma_f32_16x16x32_bf16(wh, blv[tt], Cr[tt][nt], 0, 0, 0);
        Cr[tt][nt] = __builtin_amdgcn_mfma_f32_16x16x32_bf16(wl, bhv[tt], Cr[tt][nt], 0, 0, 0);
      }
    }
  }
  const int tl = lane & 15;
  const int nq = (lane >> 4) * 4;
#pragma unroll
  for (int tt = 0; tt < 2; ++tt) {
    const int trow = wm + tt * 16 + tl;
    if (trow < rowsM) {
      const int r = blockIdx.x * 64 + trow;
      const int b2 = r / 196, n2 = r - b2 * 196;
      const long orow = (long)(b2 * SEQ + 1 + n2) * DM;
#pragma unroll
      for (int nt = 0; nt < 2; ++nt) {
        const int n = c0 + wn + nt * 16 + nq;
        const float4 bv = *(const float4*)&pb[n];
        const float4 pv = *(const float4*)&pos[(1 + n2) * DM + n];
        float o0 = Cr[tt][nt][0] + bv.x + pv.x;
        float o1 = Cr[tt][nt][1] + bv.y + pv.y;
        float o2 = Cr[tt][nt][2] + bv.z + pv.z;
        float o3 = Cr[tt][nt][3] + bv.w + pv.w;
        *(float4*)&t[orow + n] = make_float4(o0, o1, o2, o3);
        short4v hv, lv; short hs, ls;
        split2(o0, hs, ls); hv[0] = hs; lv[0] = ls;
        split2(o1, hs, ls); hv[1] = hs; lv[1] = ls;
        split2(o2, hs, ls); hv[2] = hs; lv[2] = ls;
        split2(o3, hs, ls); hv[3] = hs; lv[3] = ls;
        *(short4v*)&tfh[orow + n] = hv;
        *(short4v*)&tfl[orow + n] = lv;
      }
    }
  }
}

__global__ void cls_pos_kernel(const float* __restrict__ cls, const float* __restrict__ pos,
                               float* __restrict__ t,
                               short* __restrict__ tfh, short* __restrict__ tfl) {
  int b = blockIdx.x, d = threadIdx.x;
  float v = cls[d] + pos[d];
  t[(b * SEQ) * DM + d] = v;
  short hs, ls; split2(v, hs, ls);
  tfh[(b * SEQ) * DM + d] = hs;
  tfl[(b * SEQ) * DM + d] = ls;
}

// =====================================================================
// MFMA attention. One block per (b, h, 64-query tile); 4 waves x 16 q.
// =====================================================================
constexpr int APIT = 232;  // P row pitch (shorts)
constexpr int VPIT = 40;   // V^T row pitch (shorts)
__global__ __launch_bounds__(256) void attn_mfma_kernel(const short* __restrict__ qh,
                                                        const short* __restrict__ ql,
                                                        short* __restrict__ afh,
                                                        short* __restrict__ afl) {
  const int bh = blockIdx.x;
  const int b = bh / NHEAD, h = bh % NHEAD;
  const int q0 = blockIdx.y * 64;
  const int tid = threadIdx.x;
  const int w = tid >> 6, lane = tid & 63;
  const int tl = lane & 15, g = lane >> 4;
  __shared__ short ph[4][16 * APIT];
  __shared__ short pl[4][16 * APIT];
  __shared__ short vsh[64 * VPIT];
  __shared__ short vsl[64 * VPIT];
  const long hq = (long)h * HDIM;

  const int qrow = q0 + w * 16 + tl;
  const long qtok = (long)(b * SEQ + min(qrow, SEQ - 1)) * 1152;
  short8v qfh[2], qfl[2];
#pragma unroll
  for (int s = 0; s < 2; ++s) {
    qfh[s] = *(const short8v*)&qh[qtok + hq + s * 32 + g * 8];
    qfl[s] = *(const short8v*)&ql[qtok + hq + s * 32 + g * 8];
  }

  f32x4v sc[13];
#pragma unroll
  for (int n = 0; n < 13; ++n) {
    f32x4v acc = {};
    const long ktok = (long)(b * SEQ + min(n * 16 + tl, SEQ - 1)) * 1152;
#pragma unroll
    for (int s = 0; s < 2; ++s) {
      const short8v kh = *(const short8v*)&qh[ktok + DM + hq + s * 32 + g * 8];
      const short8v kl = *(const short8v*)&ql[ktok + DM + hq + s * 32 + g * 8];
      acc = __builtin_amdgcn_mfma_f32_16x16x32_bf16(kh, qfh[s], acc, 0, 0, 0);
      acc = __builtin_amdgcn_mfma_f32_16x16x32_bf16(kh, qfl[s], acc, 0, 0, 0);
      acc = __builtin_amdgcn_mfma_f32_16x16x32_bf16(kl, qfh[s], acc, 0, 0, 0);
    }
    sc[n] = acc;
  }

  float m = -1e30f;
#pragma unroll
  for (int n = 0; n < 13; ++n)
#pragma unroll
    for (int j = 0; j < 4; ++j) {
      const int key = n * 16 + g * 4 + j;
      float v = sc[n][j] * 0.125f;
      v = (key < SEQ) ? v : -1e30f;
      sc[n][j] = v;
      m = fmaxf(m, v);
    }
  m = fmaxf(m, __shfl_xor(m, 16));
  m = fmaxf(m, __shfl_xor(m, 32));
  float sum = 0.f;
#pragma unroll
  for (int n = 0; n < 13; ++n)
#pragma unroll
    for (int j = 0; j < 4; ++j) {
      float p = __expf(sc[n][j] - m);
      sc[n][j] = p; sum += p;
    }
  sum += __shfl_xor(sum, 16);
  sum += __shfl_xor(sum, 32);
  const float inv = 1.f / sum;

  short* prowh = &ph[w][tl * APIT];
  short* prowl = &pl[w][tl * APIT];
#pragma unroll
  for (int n = 0; n < 13; ++n) {
    short4v hv, lv;
#pragma unroll
    for (int j = 0; j < 4; ++j) {
      short hs, ls; split2(sc[n][j] * inv, hs, ls);
      hv[j] = hs; lv[j] = ls;
    }
    *(short4v*)&prowh[n * 16 + g * 4] = hv;
    *(short4v*)&prowl[n * 16 + g * 4] = lv;
  }
  {
    short4v z; z[0] = 0; z[1] = 0; z[2] = 0; z[3] = 0;
    *(short4v*)&prowh[208 + g * 4] = z;
    *(short4v*)&prowl[208 + g * 4] = z;
  }

  const int kp = (tid & 15) * 2;
  const int dg = (tid >> 4) * 4;
  f32x4v oacc[4] = {};
  short4v r0h, r0l, r1h, r1l;
  {
    const long t0 = (long)(b * SEQ + min(kp, SEQ - 1)) * 1152 + 2 * DM + hq + dg;
    const long t1 = (long)(b * SEQ + min(kp + 1, SEQ - 1)) * 1152 + 2 * DM + hq + dg;
    r0h = *(const short4v*)&qh[t0]; r0l = *(const short4v*)&ql[t0];
    r1h = *(const short4v*)&qh[t1]; r1l = *(const short4v*)&ql[t1];
  }
  for (int st = 0; st < 7; ++st) {
    __syncthreads();
#pragma unroll
    for (int jj = 0; jj < 4; ++jj) {
      short2v h2; h2[0] = r0h[jj]; h2[1] = r1h[jj];
      short2v l2; l2[0] = r0l[jj]; l2[1] = r1l[jj];
      *(short2v*)&vsh[(dg + jj) * VPIT + kp] = h2;
      *(short2v*)&vsl[(dg + jj) * VPIT + kp] = l2;
    }
    if (st + 1 < 7) {
      const int kb = (st + 1) * 32;
      const long t0 = (long)(b * SEQ + min(kb + kp, SEQ - 1)) * 1152 + 2 * DM + hq + dg;
      const long t1 = (long)(b * SEQ + min(kb + kp + 1, SEQ - 1)) * 1152 + 2 * DM + hq + dg;
      r0h = *(const short4v*)&qh[t0]; r0l = *(const short4v*)&ql[t0];
      r1h = *(const short4v*)&qh[t1]; r1l = *(const short4v*)&ql[t1];
    }
    __syncthreads();
    const short8v pbh = *(const short8v*)&prowh[st * 32 + g * 8];
    const short8v pbl = *(const short8v*)&prowl[st * 32 + g * 8];
#pragma unroll
    for (int dt = 0; dt < 4; ++dt) {
      const short8v vfh = *(const short8v*)&vsh[(dt * 16 + tl) * VPIT + g * 8];
      const short8v vfl = *(const short8v*)&vsl[(dt * 16 + tl) * VPIT + g * 8];
      oacc[dt] = __builtin_amdgcn_mfma_f32_16x16x32_bf16(vfh, pbh, oacc[dt], 0, 0, 0);
      oacc[dt] = __builtin_amdgcn_mfma_f32_16x16x32_bf16(vfh, pbl, oacc[dt], 0, 0, 0);
      oacc[dt] = __builtin_amdgcn_mfma_f32_16x16x32_bf16(vfl, pbh, oacc[dt], 0, 0, 0);
    }
  }

  if (qrow < SEQ) {
    const long obase = (long)(b * SEQ + qrow) * DM + hq;
#pragma unroll
    for (int dt = 0; dt < 4; ++dt) {
      short4v hv, lv; short hs, ls;
      split2(oacc[dt][0], hs, ls); hv[0] = hs; lv[0] = ls;
      split2(oacc[dt][1], hs, ls); hv[1] = hs; lv[1] = ls;
      split2(oacc[dt][2], hs, ls); hv[2] = hs; lv[2] = ls;
      split2(oacc[dt][3], hs, ls); hv[3] = hs; lv[3] = ls;
      *(short4v*)&afh[obase + dt * 16 + g * 4] = hv;
      *(short4v*)&afl[obase + dt * 16 + g * 4] = lv;
    }
  }
}

// ---------------- residual add + LayerNorm (per token) ----------------
__global__ __launch_bounds__(384) void add_ln_kernel(float* __restrict__ t,
                                                     const float* __restrict__ delta,
                                                     const float* __restrict__ g,
                                                     const float* __restrict__ bta,
                                                     short* __restrict__ tfh,
                                                     short* __restrict__ tfl) {
  int tok = blockIdx.x, d = threadIdx.x;
  float v = t[tok * DM + d] + delta[tok * DM + d];
  float sv = v, sq = v * v;
  for (int off = 32; off > 0; off >>= 1) { sv += __shfl_xor(sv, off); sq += __shfl_xor(sq, off); }
  __shared__ float rs[6], rq[6];
  int w = d >> 6, ln = d & 63;
  if (ln == 0) { rs[w] = sv; rq[w] = sq; }
  __syncthreads();
  float mean = 0.f, ms = 0.f;
#pragma unroll
  for (int i = 0; i < 6; i++) { mean += rs[i]; ms += rq[i]; }
  mean *= (1.f / DM); ms *= (1.f / DM);
  float inv = rsqrtf(ms - mean * mean + EPSLN);
  float y = (v - mean) * inv * g[d] + bta[d];
  t[tok * DM + d] = y;
  short hs, ls; split2(y, hs, ls);
  tfh[tok * DM + d] = hs;
  tfl[tok * DM + d] = ls;
}

// ---------------- router logits + top-2 (no global atomics) ----------------
__global__ __launch_bounds__(256) void router_logits_kernel(const float* __restrict__ t,
                                                            const float* __restrict__ rw,
                                                            const float* __restrict__ rb,
                                                            unsigned k0, unsigned k1,
                                                            float* __restrict__ gates,
                                                            int* __restrict__ idxb) {
  const int tok = blockIdx.x * 4 + (threadIdx.x >> 6);
  const int lane = threadIdx.x & 63;
  const int e = lane & 7, j = lane >> 3;
  const float* xr = t + tok * DM;
  float acc = 0.f;
  for (int d2 = j * 48; d2 < j * 48 + 48; d2++) acc += xr[d2] * rw[d2 * NEXP + e];
  acc += __shfl_xor(acc, 8);
  acc += __shfl_xor(acc, 16);
  acc += __shfl_xor(acc, 32);
  if (lane < 8) {
    acc += rb[e];
    unsigned i = (unsigned)(tok * NEXP + e);
    unsigned y0, y1;
    tf2x32(k0, k1, 0u, i, y0, y1);
    unsigned bits = y0 ^ y1;
    float f = __uint_as_float(0x3f800000u | (bits >> 9)) - 1.0f;
    const float lo = -0.99999994f;
    float u = f * 2.0f + lo;
    u = fmaxf(lo, u);
    acc += 0.01f * (1.41421356f * erfinv32(u));
  }
  float lg[8];
#pragma unroll
  for (int qq = 0; qq < 8; qq++) lg[qq] = __shfl(acc, qq);
  if (lane == 0) {
    int i0 = 0; float v0 = lg[0];
#pragma unroll
    for (int qq = 1; qq < 8; qq++) if (lg[qq] > v0) { v0 = lg[qq]; i0 = qq; }
    int i1 = -1; float v1 = -1e30f;
#pragma unroll
    for (int qq = 0; qq < 8; qq++) if (qq != i0 && lg[qq] > v1) { v1 = lg[qq]; i1 = qq; }
    float e1 = __expf(v1 - v0);
    float g0 = 1.f / (1.f + e1);
    idxb[tok * 2] = i0; idxb[tok * 2 + 1] = i1;
    gates[tok * 2] = g0; gates[tok * 2 + 1] = 1.f - g0;
  }
}

// ---------------- bucket + bias_sum (occ stays in LDS) ----------------
__global__ __launch_bounds__(1024) void bucket_kernel(const int* __restrict__ idxb,
                                                      int* __restrict__ lists,
                                                      int* __restrict__ counts,
                                                      const float* __restrict__ bias0,
                                                      float* __restrict__ bias_sum) {
  __shared__ int lc[NEXP];
  __shared__ int locc[2 * NEXP];
  const int tid = threadIdx.x;
  if (tid < NEXP) lc[tid] = 0;
  if (tid < 2 * NEXP) locc[tid] = 0;
  __syncthreads();
  for (int i = tid; i < 2 * TOK; i += 1024) {
    const int e = idxb[i];
    const int p = atomicAdd(&lc[e], 1);
    lists[e * CAPE + p] = i;
    locc[(i & 1) * NEXP + e] = 1;
  }
  __syncthreads();
  if (tid < NEXP) counts[tid] = lc[tid];
  if (tid < 2 * DM) {
    const int k = tid / DM, d = tid - k * DM;
    float acc = 0.f;
#pragma unroll
    for (int e = 0; e < NEXP; e++)
      if (locc[k * NEXP + e]) acc += bias0[e * DM + d];
    bias_sum[k * DM + d] = acc;
  }
}

// ---------------- bias0 init (all layers): bias0 = b2 ----------------
__global__ void prep_kernel(const float* __restrict__ b2, float* __restrict__ bias0) {
  const long i = ((long)blockIdx.y * NEXP + blockIdx.x) * DM + threadIdx.x;
  bias0[i] = b2[i];
}

// ---------------- bias0 += gelu(b1)@W2, batched over layers ----------------
__global__ __launch_bounds__(384) void bias0_partial_kernel(const float* __restrict__ b1,
                                                            const float* __restrict__ w2,
                                                            float* __restrict__ bias0) {
  const int e = blockIdx.x, kc = blockIdx.y, l = blockIdx.z;
  __shared__ float gb[128];
  const int tid = threadIdx.x;
  if (tid < 128) gb[tid] = gelu_f(b1[(long)l * NEXP * HIDN + e * HIDN + kc * 128 + tid]);
  __syncthreads();
  float acc = 0.f;
  const float* W = w2 + ((long)l * NEXP * HIDN + (long)e * HIDN + kc * 128) * DM + tid;
  for (int j2 = 0; j2 < 128; j2++) acc += gb[j2] * W[(long)j2 * DM];
  atomicAdd(&bias0[((long)l * NEXP + e) * DM + tid], acc);
}

// ---------------- combine experts + residual + LN2 ----------------
__global__ __launch_bounds__(384) void moe_combine_ln_kernel(float* __restrict__ t,
                                                             const float* __restrict__ ybuf,
                                                             const float* __restrict__ gates,
                                                             const int* __restrict__ idxb,
                                                             const float* __restrict__ bias0,
                                                             const float* __restrict__ bias_sum,
                                                             const float* __restrict__ g,
                                                             const float* __restrict__ bta,
                                                             short* __restrict__ tfh,
                                                             short* __restrict__ tfl) {
  int tok = blockIdx.x, d = threadIdx.x;
  float g0 = gates[tok * 2], g1 = gates[tok * 2 + 1];
  int i0 = idxb[tok * 2], i1 = idxb[tok * 2 + 1];
  float m0 = ybuf[(tok * 2) * DM + d] - bias0[i0 * DM + d] + bias_sum[d];
  float m1 = ybuf[(tok * 2 + 1) * DM + d] - bias0[i1 * DM + d] + bias_sum[DM + d];
  float v = t[tok * DM + d] + g0 * m0 + g1 * m1;
  float sv = v, sq = v * v;
  for (int off = 32; off > 0; off >>= 1) { sv += __shfl_xor(sv, off); sq += __shfl_xor(sq, off); }
  __shared__ float rs[6], rq[6];
  int w = d >> 6, ln = d & 63;
  if (ln == 0) { rs[w] = sv; rq[w] = sq; }
  __syncthreads();
  float mean = 0.f, ms = 0.f;
#pragma unroll
  for (int i = 0; i < 6; i++) { mean += rs[i]; ms += rq[i]; }
  mean *= (1.f / DM); ms *= (1.f / DM);
  float inv = rsqrtf(ms - mean * mean + EPSLN);
  float y = (v - mean) * inv * g[d] + bta[d];
  t[tok * DM + d] = y;
  short hs, ls; split2(y, hs, ls);
  tfh[tok * DM + d] = hs;
  tfl[tok * DM + d] = ls;
}

// ---------------- final: LN(cls) @ fc_w + fc_b ----------------
__global__ __launch_bounds__(256) void final_kernel(const float* __restrict__ t,
                                                    const float* __restrict__ ng,
                                                    const float* __restrict__ nb,
                                                    const float* __restrict__ fw,
                                                    const float* __restrict__ fb,
                                                    float* __restrict__ out) {
  int b = blockIdx.x, chunk = blockIdx.y, tid = threadIdx.x;
  __shared__ float xr[DM];
  __shared__ float rs[4], rq[4];
  const float* row = t + (b * SEQ) * DM;
  float sv = 0.f, sq = 0.f;
  for (int i = tid; i < DM; i += 256) { float x = row[i]; xr[i] = x; sv += x; sq += x * x; }
  for (int off = 32; off > 0; off >>= 1) { sv += __shfl_xor(sv, off); sq += __shfl_xor(sq, off); }
  int w = tid >> 6, ln = tid & 63;
  if (ln == 0) { rs[w] = sv; rq[w] = sq; }
  __syncthreads();
  float mean = (rs[0] + rs[1] + rs[2] + rs[3]) * (1.f / DM);
  float ms = (rq[0] + rq[1] + rq[2] + rq[3]) * (1.f / DM);
  float inv = rsqrtf(ms - mean * mean + EPSLN);
  for (int i = tid; i < DM; i += 256) xr[i] = (xr[i] - mean) * inv * ng[i] + nb[i];
  __syncthreads();
  int c = chunk * 250 + tid;
  if (tid < 250) {
    float acc = fb[c];
    for (int k = 0; k < DM; k++) acc += xr[k] * fw[k * NCLS + c];
    out[b * NCLS + c] = acc;
  }
}

extern "C" void kernel_launch(void* const* d_in, const int* in_sizes, int n_in,
                              void* d_out, int out_size, void* d_ws, size_t ws_size,
                              hipStream_t stream) {
  const float* x       = (const float*)d_in[0];
  const float* patch_w = (const float*)d_in[1];
  const float* patch_b = (const float*)d_in[2];
  const float* cls_tok = (const float*)d_in[3];
  const float* pos     = (const float*)d_in[4];
  const float* qkv_w   = (const float*)d_in[5];
  const float* qkv_b   = (const float*)d_in[6];
  const float* proj_w  = (const float*)d_in[7];
  const float* proj_b  = (const float*)d_in[8];
  const float* ln1_g   = (const float*)d_in[9];
  const float* ln1_b   = (const float*)d_in[10];
  const float* ln2_g   = (const float*)d_in[11];
  const float* ln2_b   = (const float*)d_in[12];
  const float* router_w = (const float*)d_in[13];
  const float* router_b = (const float*)d_in[14];
  const float* w1      = (const float*)d_in[15];
  const float* b1      = (const float*)d_in[16];
  const float* w2      = (const float*)d_in[17];
  const float* b2      = (const float*)d_in[18];
  const float* norm_g  = (const float*)d_in[19];
  const float* norm_b  = (const float*)d_in[20];
  const float* fc_w    = (const float*)d_in[21];
  const float* fc_b    = (const float*)d_in[22];

  float* ws = (float*)d_ws;
  float* t        = ws;                      // TOK*DM
  float* proj     = t + TOK * DM;            // TOK*DM
  float* ybuf     = proj + TOK * DM;         // TOK*2*DM
  float* bias0    = ybuf + TOK * 2 * DM;     // LYR*NEXP*DM
  float* bias_sum = bias0 + LYR * NEXP * DM; // 2*DM
  float* gates    = bias_sum + 2 * DM;       // TOK*2
  int* idxb   = (int*)(gates + TOK * 2);     // TOK*2
  int* lists  = idxb + TOK * 2;              // NEXP*CAPE
  int* counts = lists + NEXP * CAPE;         // NEXP (+pad to even)
  short* tfh = (short*)(counts + 8);         // TOK*DM (16B-aligned)
  short* tfl = tfh + TOK * DM;
  short* afh = tfl + TOK * DM;
  short* afl = afh + TOK * DM;
  short* qvh = afl + TOK * DM;               // TOK*1152
  short* qvl = qvh + TOK * 1152;             // TOK*1152
  short* hbh = qvl + TOK * 1152;             // 2*TOK*HIDN
  short* hbl = hbh + 2 * TOK * HIDN;         // 2*TOK*HIDN
  short* wqf = hbl + 2 * TOK * HIDN;         // LYR*864*1024
  short* wpf = wqf + (long)LYR * 864 * 1024;        // LYR*288*1024
  short* w1f = wpf + (long)LYR * 288 * 1024;        // LYR*8*1152*1024
  short* w2f = w1f + (long)LYR * NEXP * 1152 * 1024; // LYR*8*1152*1024
  short* wpatf = w2f + (long)LYR * NEXP * 1152 * 1024; // 576*1024

  // ---- upfront: weight conversions (all layers), bias0 (all layers) ----
  convw_kernel<<<dim3(144, 1, 1), 256, 0, stream>>>(patch_w, wpatf, 768, DM, 0, 0);
  convw_kernel<<<dim3(216, 1, LYR), 256, 0, stream>>>(qkv_w, wqf, DM, 1152,
                                                      (long)DM * 1152, 864L * 1024);
  convw_kernel<<<dim3(72, 1, LYR), 256, 0, stream>>>(proj_w, wpf, DM, DM,
                                                     (long)DM * DM, 288L * 1024);
  convw_kernel<<<dim3(288, NEXP, LYR), 256, 0, stream>>>(w1, w1f, DM, HIDN,
                                                         (long)NEXP * DM * HIDN,
                                                         (long)NEXP * 1152 * 1024);
  convw_kernel<<<dim3(288, NEXP, LYR), 256, 0, stream>>>(w2, w2f, HIDN, DM,
                                                         (long)NEXP * HIDN * DM,
                                                         (long)NEXP * 1152 * 1024);
  prep_kernel<<<dim3(NEXP, LYR), DM, 0, stream>>>(b2, bias0);
  bias0_partial_kernel<<<dim3(NEXP, 12, LYR), 384, 0, stream>>>(b1, w2, bias0);

  patch_mfma_kernel<<<dim3(25, 1, 6), 256, 0, stream>>>(x, wpatf, patch_b, pos, t, tfh, tfl);
  cls_pos_kernel<<<BATCH, DM, 0, stream>>>(cls_tok, pos, t, tfh, tfl);

  for (int l = 0; l < LYR; l++) {
    const short* wqf_l = wqf + (long)l * 864 * 1024;
    const short* wpf_l = wpf + (long)l * 288 * 1024;
    const short* w1f_l = w1f + (long)l * NEXP * 1152 * 1024;
    const short* w2f_l = w2f + (long)l * NEXP * 1152 * 1024;
    const float* bias0_l = bias0 + (long)l * NEXP * DM;

    gemm_lds_kernel<DM, 1152, 3><<<dim3(24, 25), 256, 0, stream>>>(
        tfh, tfl, wqf_l, qkv_b + l * 1152, nullptr, nullptr, nullptr, qvh, qvl);
    attn_mfma_kernel<<<dim3(BATCH * NHEAD, 4), 256, 0, stream>>>(qvh, qvl, afh, afl);
    gemm_lds_kernel<DM, DM, 0><<<dim3(8, 25), 256, 0, stream>>>(
        afh, afl, wpf_l, proj_b + l * DM, nullptr, nullptr, proj, nullptr, nullptr);
    add_ln_kernel<<<TOK, DM, 0, stream>>>(t, proj, ln1_g + l * DM, ln1_b + l * DM, tfh, tfl);

    unsigned kl0, kl1;
    tf2x32(0u, 42u, 0u, (unsigned)l, kl0, kl1);
    router_logits_kernel<<<TOK / 4, 256, 0, stream>>>(
        t, router_w + l * DM * NEXP, router_b + l * NEXP, kl0, kl1, gates, idxb);
    bucket_kernel<<<1, 1024, 0, stream>>>(idxb, lists, counts, bias0_l, bias_sum);
    gemm_lds_kernel<DM, HIDN, 1><<<dim3(192, 25), 256, 0, stream>>>(
        tfh, tfl, w1f_l, b1 + l * NEXP * HIDN, lists, counts, nullptr, hbh, hbl);
    gemm_lds_kernel<HIDN, DM, 2><<<dim3(48, 25), 256, 0, stream>>>(
        hbh, hbl, w2f_l, b2 + l * NEXP * DM, lists, counts, ybuf, nullptr, nullptr);
    moe_combine_ln_kernel<<<TOK, DM, 0, stream>>>(t, ybuf, gates, idxb, bias0_l, bias_sum,
                                                  ln2_g + l * DM, ln2_b + l * DM, tfh, tfl);
  }

  final_kernel<<<dim3(BATCH, 4), 256, 0, stream>>>(t, norm_g, norm_b, fc_w, fc_b,
                                                   (float*)d_out);
}